// Round 13
// baseline (2219.583 us; speedup 1.0000x reference)
//
#include <hip/hip_runtime.h>

#define NN 50000
#define NE 600000
#define HD 128
#define NL 6
#define DPB 16   // dsts per block (NN/DPB = 3125 exact)

typedef __attribute__((ext_vector_type(8))) short bf16x8;
typedef __attribute__((ext_vector_type(4))) float f32x4;

__device__ inline unsigned short f2bf(float x) {
  unsigned u = __float_as_uint(x);
  u += 0x7FFF + ((u >> 16) & 1);           // RNE on raw bits
  return (unsigned short)(u >> 16);
}
__device__ inline float bf2f(unsigned short s) {
  return __uint_as_float((unsigned)s << 16);
}
__device__ inline unsigned pk2(float a, float b) {
  return (unsigned)f2bf(a) | ((unsigned)f2bf(b) << 16);
}

__global__ void k_code(float* __restrict__ out, float code) {
  if (threadIdx.x == 0 && blockIdx.x == 0) out[0] = code;
}

// ---------------- weight transposes -> bf16 [layer][n][k] ----------------

__global__ __launch_bounds__(256) void k_w2t(const float* __restrict__ W, unsigned short* __restrict__ T) {
  int idx = blockIdx.x * 256 + threadIdx.x;
  if (idx >= NL * HD * HD) return;
  int l = idx >> 14, r = idx & 16383;
  int n = r >> 7, k = r & 127;
  T[idx] = f2bf(W[(l << 14) + (k << 7) + n]);
}

__global__ __launch_bounds__(256) void k_u1t(const float* __restrict__ W, unsigned short* __restrict__ T) {
  int idx = blockIdx.x * 256 + threadIdx.x;
  if (idx >= NL * 128 * 256) return;
  int l = idx >> 15, r = idx & 32767;
  int n = r >> 8, k = r & 255;
  T[idx] = f2bf(W[l * 32896 + k * 128 + n]);
}

__global__ __launch_bounds__(256) void k_abt(const float* __restrict__ W, unsigned short* __restrict__ T) {
  int idx = blockIdx.x * 256 + threadIdx.x;
  if (idx >= NL * 256 * 128) return;
  int l = idx >> 15, r = idx & 32767;
  int n = r >> 7, k = r & 127;
  int row = (n < 128) ? k : 128 + k;
  int col = n & 127;
  T[idx] = f2bf(W[l * 33280 + row * 128 + col]);
}

// ---------------- degree histogram, scan, counting sort (by dst) ----------------

__global__ __launch_bounds__(256) void k_deg(const int* __restrict__ ei, int* __restrict__ deg) {
  int e = blockIdx.x * 256 + threadIdx.x;
  if (e < NE) {
    int d = ei[NE + e];
    if (d >= 0 && d < NN) atomicAdd(&deg[d], 1);
  }
}

__global__ __launch_bounds__(256) void k_scan1(const int* __restrict__ deg, int* __restrict__ cursor,
                                               int* __restrict__ blk, float* __restrict__ invd) {
  __shared__ int sd[256];
  int t = threadIdx.x;
  int i = blockIdx.x * 256 + t;
  int v = (i < NN) ? deg[i] : 0;
  sd[t] = v;
  __syncthreads();
  for (int off = 1; off < 256; off <<= 1) {
    int x = (t >= off) ? sd[t - off] : 0;
    __syncthreads();
    if (t >= off) sd[t] += x;
    __syncthreads();
  }
  int incl = sd[t];
  if (i < NN) {
    cursor[i] = incl - v;
    invd[i] = 1.0f / fmaxf((float)v, 1.0f);
  }
  if (t == 255) blk[blockIdx.x] = incl;
}

__global__ __launch_bounds__(256) void k_scan2(int* __restrict__ blk, int nb) {
  __shared__ int sd[256];
  int t = threadIdx.x;
  int v = (t < nb) ? blk[t] : 0;
  sd[t] = v;
  __syncthreads();
  for (int off = 1; off < 256; off <<= 1) {
    int x = (t >= off) ? sd[t - off] : 0;
    __syncthreads();
    if (t >= off) sd[t] += x;
    __syncthreads();
  }
  if (t < nb) blk[t] = sd[t] - v;
}

__global__ __launch_bounds__(256) void k_scan3(int* __restrict__ cursor, const int* __restrict__ blk,
                                               int* __restrict__ rowstart) {
  int i = blockIdx.x * 256 + threadIdx.x;
  if (i < NN) {
    int v = cursor[i] + blk[blockIdx.x];
    cursor[i] = v;
    rowstart[i] = v;
  }
  if (i == 0) rowstart[NN] = NE;
}

__global__ __launch_bounds__(256) void k_scatter(const int* __restrict__ ei, const float* __restrict__ u,
                                                 const float* __restrict__ pos, int* __restrict__ cursor,
                                                 int* __restrict__ ssrc, int* __restrict__ sdst,
                                                 float* __restrict__ sfeat) {
  int e = blockIdx.x * 256 + threadIdx.x;
  if (e >= NE) return;
  int s = ei[e], d = ei[NE + e];
  s = s < 0 ? 0 : (s >= NN ? NN - 1 : s);
  d = d < 0 ? 0 : (d >= NN ? NN - 1 : d);
  int p = atomicAdd(&cursor[d], 1);
  ssrc[p] = s;
  sdst[p] = d;
  float du  = u[d] - u[s];
  float dpx = pos[d*3+1] - pos[s*3+1];
  float dpy = pos[d*3+2] - pos[s*3+2];
  float vi  = pos[d*3+0];
  ((float4*)sfeat)[p] = make_float4(du, dpx, dpy, vi);
}

// ---------------- embedding (per-block partial stats -> P) ----------------

__global__ __launch_bounds__(256) void k_emb1(const float* __restrict__ u, const float* __restrict__ pos,
                                              const float* __restrict__ W, const float* __restrict__ b,
                                              float* __restrict__ h, double* __restrict__ P) {
  __shared__ float xs[32 * 129];
  int tid = threadIdx.x;
  int nl = tid & 31, jg = tid >> 5;
  int gn = blockIdx.x * 32 + nl;
  float f0 = 0.f, f1 = 0.f, f2 = 0.f, f3 = 0.f;
  if (gn < NN) { f0 = u[gn]; f1 = pos[gn*3+1]; f2 = pos[gn*3+2]; f3 = pos[gn*3+0]; }
  float x[16];
#pragma unroll
  for (int q = 0; q < 4; ++q) {
    int j = (jg << 4) + (q << 2);
    float4 w0 = *(const float4*)(W + 0*HD + j);
    float4 w1 = *(const float4*)(W + 1*HD + j);
    float4 w2 = *(const float4*)(W + 2*HD + j);
    float4 w3 = *(const float4*)(W + 3*HD + j);
    float4 bb = *(const float4*)(b + j);
    x[q*4+0] = f0*w0.x + f1*w1.x + f2*w2.x + f3*w3.x + bb.x;
    x[q*4+1] = f0*w0.y + f1*w1.y + f2*w2.y + f3*w3.y + bb.y;
    x[q*4+2] = f0*w0.z + f1*w1.z + f2*w2.z + f3*w3.z + bb.z;
    x[q*4+3] = f0*w0.w + f1*w1.w + f2*w2.w + f3*w3.w + bb.w;
  }
  if (gn < NN) {
#pragma unroll
    for (int q = 0; q < 4; ++q)
      *(float4*)(h + (size_t)gn*HD + (jg<<4) + (q<<2)) = make_float4(x[q*4+0], x[q*4+1], x[q*4+2], x[q*4+3]);
  }
#pragma unroll
  for (int i = 0; i < 16; ++i) xs[nl*129 + (jg<<4) + i] = (gn < NN) ? x[i] : 0.f;
  __syncthreads();
  if (tid < HD) {
    double s = 0.0, sq = 0.0;
    for (int e = 0; e < 32; ++e) { double v = (double)xs[e*129 + tid]; s += v; sq += v*v; }
    size_t pb = (size_t)blockIdx.x * 256;
    P[pb + tid] = s;
    P[pb + 128 + tid] = sq;
  }
}

__global__ __launch_bounds__(256) void k_emb2(float* __restrict__ h, const float* __restrict__ W,
                                              const float* __restrict__ b, double* __restrict__ P) {
  __shared__ float hs[32 * 129];
  int tid = threadIdx.x;
  int base = blockIdx.x * 32;
#pragma unroll
  for (int r = 0; r < 16; ++r) {
    int lin = r*256 + tid;
    int n = lin >> 7, j = lin & 127;
    int gn = base + n;
    hs[n*129 + j] = (gn < NN) ? h[(size_t)gn*HD + j] : 0.f;
  }
  __syncthreads();
  int nl = tid & 31, jg = tid >> 5;
  int gn = base + nl;
  float acc[16];
#pragma unroll
  for (int q = 0; q < 4; ++q) {
    float4 bb = *(const float4*)(b + (jg<<4) + (q<<2));
    acc[q*4+0] = bb.x; acc[q*4+1] = bb.y; acc[q*4+2] = bb.z; acc[q*4+3] = bb.w;
  }
  for (int k = 0; k < HD; ++k) {
    float a = hs[nl*129 + k];
    const float4* wp = (const float4*)(W + (size_t)k*HD + (jg<<4));
#pragma unroll
    for (int q = 0; q < 4; ++q) {
      float4 wv = wp[q];
      acc[q*4+0] = fmaf(a, wv.x, acc[q*4+0]);
      acc[q*4+1] = fmaf(a, wv.y, acc[q*4+1]);
      acc[q*4+2] = fmaf(a, wv.z, acc[q*4+2]);
      acc[q*4+3] = fmaf(a, wv.w, acc[q*4+3]);
    }
  }
  if (gn < NN) {
#pragma unroll
    for (int q = 0; q < 4; ++q)
      *(float4*)(h + (size_t)gn*HD + (jg<<4) + (q<<2)) = make_float4(acc[q*4+0], acc[q*4+1], acc[q*4+2], acc[q*4+3]);
  }
  __syncthreads();
#pragma unroll
  for (int i = 0; i < 16; ++i) hs[nl*129 + (jg<<4) + i] = (gn < NN) ? acc[i] : 0.f;
  __syncthreads();
  if (tid < HD) {
    double s = 0.0, sq = 0.0;
    for (int e = 0; e < 32; ++e) { double v = (double)hs[e*129 + tid]; s += v; sq += v*v; }
    size_t pb = (size_t)blockIdx.x * 256;
    P[pb + tid] = s;
    P[pb + 128 + tid] = sq;
  }
}

// reduce P[nrows][256] -> musig (one block per channel)
__global__ __launch_bounds__(256) void k_redP(const double* __restrict__ P, int nrows,
                                              float* __restrict__ musig) {
  __shared__ double sd[256];
  __shared__ double sq_[256];
  int c = blockIdx.x;       // 0..127
  int t = threadIdx.x;
  double s = 0.0, q = 0.0;
  for (int k = t; k < nrows; k += 256) {
    s += P[(size_t)k*256 + c];
    q += P[(size_t)k*256 + 128 + c];
  }
  sd[t] = s; sq_[t] = q;
  __syncthreads();
  for (int off = 128; off; off >>= 1) {
    if (t < off) { sd[t] += sd[t + off]; sq_[t] += sq_[t + off]; }
    __syncthreads();
  }
  if (t == 0) {
    double mu  = sd[0] / (double)NN;
    double var = sq_[0] / (double)NN - mu * mu;
    musig[c]      = (float)mu;
    musig[HD + c] = (float)(1.0 / sqrt(var + 1e-5));
  }
}

__global__ void k_redA(const double* __restrict__ stats, float* __restrict__ musig) {
  int c = threadIdx.x;   // 128
  double mu  = stats[c] / (double)NN;
  double var = stats[128 + c] / (double)NN - mu * mu;
  musig[c]      = (float)mu;
  musig[HD + c] = (float)(1.0 / sqrt(var + 1e-5));
}

__global__ __launch_bounds__(256) void k_bn(float* __restrict__ h, const float* __restrict__ musig,
                                            const float* __restrict__ g, const float* __restrict__ be,
                                            int relu) {
  int idx = blockIdx.x * 256 + threadIdx.x;
  if (idx >= NN * HD) return;
  int j = idx & 127;
  float x = h[idx];
  x = g[j] * (x - musig[j]) * musig[HD + j] + be[j];
  if (relu) x = fmaxf(x, 0.f);
  h[idx] = x;
}

// ---------------- k_ab via MFMA, fused BN of previous layer, bf16 A/B output ----------------

__global__ __launch_bounds__(256) void k_ab_mfma(float* __restrict__ h,
                                                 const unsigned short* __restrict__ abt,
                                                 const float* __restrict__ musig,
                                                 const float* __restrict__ g, const float* __restrict__ be,
                                                 int applyBN,
                                                 unsigned short* __restrict__ A, unsigned short* __restrict__ B) {
  __shared__ unsigned short hbf[32 * 136];
  int tid = threadIdx.x;
  int base = blockIdx.x * 32;
#pragma unroll
  for (int r = 0; r < 16; ++r) {
    int lin = r*256 + tid;
    int n = lin >> 7, j = lin & 127;
    int gn = base + n;
    float hv = (gn < NN) ? h[(size_t)gn*HD + j] : 0.f;
    if (applyBN) {
      hv = g[j] * (hv - musig[j]) * musig[HD + j] + be[j];
      if (gn < NN) h[(size_t)gn*HD + j] = hv;
    }
    hbf[n*136 + j] = f2bf((gn < NN) ? hv : 0.f);
  }
  __syncthreads();
  int wv = tid >> 6, lane = tid & 63;
  int quad = lane >> 4, mrow = lane & 15;
  int mt = wv & 1, ntg = wv >> 1;
  f32x4 acc[8];
#pragma unroll
  for (int t = 0; t < 8; ++t) acc[t] = (f32x4){0.f,0.f,0.f,0.f};
#pragma unroll
  for (int ks = 0; ks < 4; ++ks) {
    bf16x8 a = *(const bf16x8*)(hbf + (mt*16 + mrow)*136 + ks*32 + quad*8);
#pragma unroll
    for (int t = 0; t < 8; ++t) {
      bf16x8 b = *(const bf16x8*)(abt + (size_t)((ntg*8 + t)*16 + mrow)*128 + ks*32 + quad*8);
      acc[t] = __builtin_amdgcn_mfma_f32_16x16x32_bf16(a, b, acc[t], 0, 0, 0);
    }
  }
#pragma unroll
  for (int t = 0; t < 8; ++t) {
    int c = (ntg*8 + t)*16 + mrow;
#pragma unroll
    for (int r = 0; r < 4; ++r) {
      int gn = base + mt*16 + quad*4 + r;
      if (gn < NN) {
        if (c < 128) A[(size_t)gn*HD + c]       = f2bf(acc[t][r]);
        else         B[(size_t)gn*HD + c - 128] = f2bf(acc[t][r]);
      }
    }
  }
}

// ---------------- FUSED per-dst-block message + aggregate + node-update ----------------
// R10 structure (16 dsts/block, 3125 blocks); 32-edge chunks; meta prefetch 2 chunks
// ahead, B-gather issued at chunk top (1 ahead). m2bf stride 40, u32-packed writes.
// BN stats via per-block partial store to P. launch_bounds(256,4): 4 blocks/CU resident.

__global__ __launch_bounds__(256, 4) void k_msgupd(const unsigned short* __restrict__ A,
                                                   const unsigned short* __restrict__ B,
                                                   const int* __restrict__ ssrc, const int* __restrict__ sdst,
                                                   const float* __restrict__ sfeat, const float* __restrict__ invd,
                                                   const int* __restrict__ rowstart,
                                                   const float* __restrict__ W1, const float* __restrict__ b1,
                                                   const unsigned short* __restrict__ w2t, const float* __restrict__ b2,
                                                   float* __restrict__ h, const float* __restrict__ pos,
                                                   const unsigned short* __restrict__ u1t,
                                                   const float* __restrict__ U1var, const float* __restrict__ ub1,
                                                   const unsigned short* __restrict__ u2t, const float* __restrict__ ub2,
                                                   double* __restrict__ P) {
  __shared__ __align__(16) unsigned short smAB[16*136 + 32*136];  // As | m1bf ; epilogue abf[16][264]
  __shared__ __align__(16) unsigned short smD[128 * 40];          // m2bf ; epilogue u1bf[16][136]
  __shared__ float wes[6 * 128];                                   // W1-edge rows 0-3, b1, b2
  __shared__ int ldstD[64];                                        // dbuf dst-local ids (999 = invalid)

  unsigned short* As   = smAB;
  unsigned short* m1bf = smAB + 16*136;
  unsigned short* abf  = smAB;              // epilogue alias [16][264]
  unsigned short* m2bf = smD;
  unsigned short* u1bf = smD;               // epilogue alias [16][136]

  int tid = threadIdx.x;
  int base = blockIdx.x * DPB;

  // ---- phase 0: stage As (16x128 bf16, one bf16x8 per thread), weights ----
  {
    int row = tid >> 4, c16 = tid & 15;
    int gn = base + row;
    bf16x8 v = (bf16x8){0,0,0,0,0,0,0,0};
    if (gn < NN) v = *(const bf16x8*)(A + (size_t)gn*HD + c16*8);
    *(bf16x8*)(As + row*136 + c16*8) = v;
  }
  for (int i = tid; i < 768; i += 256) {
    int k = i >> 7, j = i & 127;
    float v;
    if (k < 4)       v = W1[(size_t)(256 + k)*HD + j];
    else if (k == 4) v = b1[j];
    else             v = b2[j];
    wes[i] = v;
  }
  int rs0 = rowstart[base];
  int rs1 = rowstart[base + DPB];   // base+DPB <= NN always (NN % DPB == 0)
  __syncthreads();

  int wv = tid >> 6, lane = tid & 63;
  int quad = lane >> 4, mrow = lane & 15;
  int mt = wv & 1, ntg = wv >> 1;
  int el = tid & 31, jg = tid >> 5;

  const float4* sf4 = (const float4*)sfeat;
  int nch = (rs1 - rs0 + 31) >> 5;

  f32x4 aggA[4];
#pragma unroll
  for (int t = 0; t < 4; ++t) aggA[t] = (f32x4){0.f,0.f,0.f,0.f};

  // ---- prologue: meta(0), meta(1); B(0) ----
  int d_c; float4 f_c;
  int s_n1, d_n1; float4 f_n1;
  {
    int e = rs0 + el; bool v = e < rs1;
    int sc = v ? ssrc[e] : 0;
    d_c = v ? (sdst[e] - base) : 999;
    f_c = v ? sf4[e] : make_float4(0.f, 0.f, 0.f, 0.f);
    s_n1 = sc;  // temp reuse to load B(0)
  }
  bf16x8 b0_c = *(const bf16x8*)(B + (size_t)s_n1*HD + (jg<<4));
  bf16x8 b1_c = *(const bf16x8*)(B + (size_t)s_n1*HD + (jg<<4) + 8);
  {
    int e = rs0 + 32 + el; bool v = e < rs1;
    s_n1 = v ? ssrc[e] : 0;
    d_n1 = v ? (sdst[e] - base) : 999;
    f_n1 = v ? sf4[e] : make_float4(0.f, 0.f, 0.f, 0.f);
  }

  int par = 0;
  for (int ch = 0; ch < nch; ++ch) {
    int e0 = rs0 + ch*32;
    // issue meta(ch+2)
    int s_n2, d_n2; float4 f_n2;
    {
      int e = e0 + 64 + el; bool v = e < rs1;
      s_n2 = v ? ssrc[e] : 0;
      d_n2 = v ? (sdst[e] - base) : 999;
      f_n2 = v ? sf4[e] : make_float4(0.f, 0.f, 0.f, 0.f);
    }
    // issue B(ch+1) NOW (s_n1 arrived during previous chunk) -> m1 covers its latency
    bf16x8 b0_n = *(const bf16x8*)(B + (size_t)s_n1*HD + (jg<<4));
    bf16x8 b1_n = *(const bf16x8*)(B + (size_t)s_n1*HD + (jg<<4) + 8);

    if (tid < 32) ldstD[par*32 + tid] = d_c;

    // ---- phase 1: m1 -> m1bf ----
    {
      int dA = (d_c < DPB) ? d_c : 0;
      float f0 = f_c.x, f1 = f_c.y, f2 = f_c.z, f3 = f_c.w;
      const unsigned short* Ar = As + dA*136 + (jg<<4);
      bf16x8 a0 = *(const bf16x8*)(Ar);
      bf16x8 a1 = *(const bf16x8*)(Ar + 8);
      float m1v[16];
#pragma unroll
      for (int q = 0; q < 4; ++q) {
        float4 w0 = *(const float4*)(wes + 0*128 + (jg<<4) + (q<<2));
        float4 w1 = *(const float4*)(wes + 1*128 + (jg<<4) + (q<<2));
        float4 w2 = *(const float4*)(wes + 2*128 + (jg<<4) + (q<<2));
        float4 w3 = *(const float4*)(wes + 3*128 + (jg<<4) + (q<<2));
        float4 bb = *(const float4*)(wes + 4*128 + (jg<<4) + (q<<2));
#pragma unroll
        for (int z = 0; z < 4; ++z) {
          int i = q*4 + z;
          unsigned short avs = (i < 8) ? (unsigned short)a0[i] : (unsigned short)a1[i-8];
          unsigned short bvs = (i < 8) ? (unsigned short)b0_c[i] : (unsigned short)b1_c[i-8];
          float we  = (z==0?w0.x:(z==1?w0.y:(z==2?w0.z:w0.w)));
          float w1e = (z==0?w1.x:(z==1?w1.y:(z==2?w1.z:w1.w)));
          float w2e = (z==0?w2.x:(z==1?w2.y:(z==2?w2.z:w2.w)));
          float w3e = (z==0?w3.x:(z==1?w3.y:(z==2?w3.z:w3.w)));
          float bbe = (z==0?bb.x:(z==1?bb.y:(z==2?bb.z:bb.w)));
          m1v[i] = fmaxf(bf2f(avs) + bf2f(bvs) + f0*we + f1*w1e + f2*w2e + f3*w3e + bbe, 0.f);
        }
      }
      unsigned* pp = (unsigned*)(m1bf + el*136 + (jg<<4));
#pragma unroll
      for (int i = 0; i < 8; ++i)
        pp[i] = pk2(m1v[2*i], m1v[2*i+1]);
    }
    __syncthreads();   // bar1: m1bf ready (drains prefetches; m1 covered them)

    // ---- phase 2: m2 MFMA -> relu -> m2bf [col][edge] (stride 40, u32-packed) ----
    {
      f32x4 acc0 = (f32x4){0.f,0.f,0.f,0.f}, acc1 = acc0, acc2 = acc0, acc3 = acc0;
#pragma unroll
      for (int ks = 0; ks < 4; ++ks) {
        bf16x8 a = *(const bf16x8*)(m1bf + (mt*16 + mrow)*136 + ks*32 + quad*8);
        bf16x8 bf0 = *(const bf16x8*)(w2t + ((ntg*4+0)*16 + mrow)*128 + ks*32 + quad*8);
        bf16x8 bf1 = *(const bf16x8*)(w2t + ((ntg*4+1)*16 + mrow)*128 + ks*32 + quad*8);
        bf16x8 bf2 = *(const bf16x8*)(w2t + ((ntg*4+2)*16 + mrow)*128 + ks*32 + quad*8);
        bf16x8 bf3 = *(const bf16x8*)(w2t + ((ntg*4+3)*16 + mrow)*128 + ks*32 + quad*8);
        acc0 = __builtin_amdgcn_mfma_f32_16x16x32_bf16(a, bf0, acc0, 0, 0, 0);
        acc1 = __builtin_amdgcn_mfma_f32_16x16x32_bf16(a, bf1, acc1, 0, 0, 0);
        acc2 = __builtin_amdgcn_mfma_f32_16x16x32_bf16(a, bf2, acc2, 0, 0, 0);
        acc3 = __builtin_amdgcn_mfma_f32_16x16x32_bf16(a, bf3, acc3, 0, 0, 0);
      }
      f32x4 av4[4] = {acc0, acc1, acc2, acc3};
      int ebase = mt*16 + quad*4;
#pragma unroll
      for (int t = 0; t < 4; ++t) {
        int c = (ntg*4 + t)*16 + mrow;
        float bb = wes[5*128 + c];
        unsigned q0 = pk2(fmaxf(av4[t][0] + bb, 0.f), fmaxf(av4[t][1] + bb, 0.f));
        unsigned q1 = pk2(fmaxf(av4[t][2] + bb, 0.f), fmaxf(av4[t][3] + bb, 0.f));
        unsigned* mp = (unsigned*)(m2bf + c*40 + ebase);
        mp[0] = q0; mp[1] = q1;
      }
    }
    __syncthreads();   // bar2: m2bf ready

    // ---- phase 3: selection MFMA accumulates agg in registers ----
    {
      int myrow = mt*16 + mrow;
      bf16x8 sel;
#pragma unroll
      for (int i = 0; i < 8; ++i) {
        int dl = ldstD[par*32 + quad*8 + i];
        sel[i] = (short)((dl == myrow) ? 0x3F80 : 0);
      }
      bf16x8 p0 = *(const bf16x8*)(m2bf + ((ntg*4+0)*16 + mrow)*40 + quad*8);
      bf16x8 p1 = *(const bf16x8*)(m2bf + ((ntg*4+1)*16 + mrow)*40 + quad*8);
      bf16x8 p2 = *(const bf16x8*)(m2bf + ((ntg*4+2)*16 + mrow)*40 + quad*8);
      bf16x8 p3 = *(const bf16x8*)(m2bf + ((ntg*4+3)*16 + mrow)*40 + quad*8);
      aggA[0] = __builtin_amdgcn_mfma_f32_16x16x32_bf16(sel, p0, aggA[0], 0, 0, 0);
      aggA[1] = __builtin_amdgcn_mfma_f32_16x16x32_bf16(sel, p1, aggA[1], 0, 0, 0);
      aggA[2] = __builtin_amdgcn_mfma_f32_16x16x32_bf16(sel, p2, aggA[2], 0, 0, 0);
      aggA[3] = __builtin_amdgcn_mfma_f32_16x16x32_bf16(sel, p3, aggA[3], 0, 0, 0);
    }

    // shift pipeline
    d_c = d_n1; f_c = f_n1;
    s_n1 = s_n2; d_n1 = d_n2; f_n1 = f_n2;
    b0_c = b0_n; b1_c = b1_n;
    par ^= 1;
  }

  // ================= fused 16-row update MLP =================
  // stage h (bf16) -> abf cols 0..127 (16 rows x 16 chunks = 256 threads)
  {
    int row = tid >> 4, c16 = tid & 15;
    int gn = base + row;   // always < NN
    float4 h0 = *(const float4*)(h + (size_t)gn*HD + c16*8);
    float4 h1 = *(const float4*)(h + (size_t)gn*HD + c16*8 + 4);
    unsigned* q = (unsigned*)(abf + row*264 + c16*8);
    q[0] = pk2(h0.x, h0.y); q[1] = pk2(h0.z, h0.w);
    q[2] = pk2(h1.x, h1.y); q[3] = pk2(h1.z, h1.w);
  }
  // stage agg*invd -> abf cols 128..255 (only mt==0 waves hold real agg: rows 0..15)
  if (mt == 0) {
    float invdv[4];
#pragma unroll
    for (int r = 0; r < 4; ++r) invdv[r] = invd[base + quad*4 + r];
#pragma unroll
    for (int t = 0; t < 4; ++t) {
      int c = (ntg*4 + t)*16 + mrow;
#pragma unroll
      for (int r = 0; r < 4; ++r)
        abf[(quad*4 + r)*264 + 128 + c] = f2bf(aggA[t][r] * invdv[r]);
    }
  }
  __syncthreads();   // abf ready

  int lo = mrow;     // lane & 15
  float ub1c[2], uvarc[2], ub2c[2];
#pragma unroll
  for (int t = 0; t < 2; ++t) {
    int c = (wv*2 + t)*16 + lo;
    ub1c[t] = ub1[c]; uvarc[t] = U1var[c]; ub2c[t] = ub2[c];
  }
  float lvarv[4];
#pragma unroll
  for (int r = 0; r < 4; ++r) lvarv[r] = pos[(size_t)(base + quad*4 + r)*3 + 0];

  // u1: [h|agg] (16x256) @ u1t -> relu -> u1bf
  f32x4 ua[2];
  ua[0] = (f32x4){0.f,0.f,0.f,0.f}; ua[1] = ua[0];
#pragma unroll
  for (int ks = 0; ks < 8; ++ks) {
    bf16x8 a = *(const bf16x8*)(abf + lo*264 + ks*32 + quad*8);
#pragma unroll
    for (int t = 0; t < 2; ++t) {
      bf16x8 b = *(const bf16x8*)(u1t + (size_t)((wv*2 + t)*16 + lo)*256 + ks*32 + quad*8);
      ua[t] = __builtin_amdgcn_mfma_f32_16x16x32_bf16(a, b, ua[t], 0, 0, 0);
    }
  }
#pragma unroll
  for (int t = 0; t < 2; ++t) {
    int c = (wv*2 + t)*16 + lo;
#pragma unroll
    for (int r = 0; r < 4; ++r) {
      float v = fmaxf(ua[t][r] + ub1c[t] + lvarv[r]*uvarc[t], 0.f);
      u1bf[(quad*4 + r)*136 + c] = f2bf(v);
    }
  }
  __syncthreads();   // u1bf ready

  // u2: u1 (16x128) @ u2t
  f32x4 va[2];
  va[0] = (f32x4){0.f,0.f,0.f,0.f}; va[1] = va[0];
#pragma unroll
  for (int ks = 0; ks < 4; ++ks) {
    bf16x8 a = *(const bf16x8*)(u1bf + lo*136 + ks*32 + quad*8);
#pragma unroll
    for (int t = 0; t < 2; ++t) {
      bf16x8 b = *(const bf16x8*)(u2t + (size_t)((wv*2 + t)*16 + lo)*128 + ks*32 + quad*8);
      va[t] = __builtin_amdgcn_mfma_f32_16x16x32_bf16(a, b, va[t], 0, 0, 0);
    }
  }

  // residual + h write + BN partial stats -> P
#pragma unroll
  for (int t = 0; t < 2; ++t) {
    int c = (wv*2 + t)*16 + lo;
    float s = 0.f, q = 0.f;
#pragma unroll
    for (int r = 0; r < 4; ++r) {
      int gn = base + quad*4 + r;   // always < NN
      float x = h[(size_t)gn*HD + c] + fmaxf(va[t][r] + ub2c[t], 0.f);
      h[(size_t)gn*HD + c] = x;
      s += x; q += x*x;
    }
    s += __shfl_xor(s, 16); q += __shfl_xor(q, 16);
    s += __shfl_xor(s, 32); q += __shfl_xor(q, 32);
    if (quad == 0) {
      size_t pb = (size_t)blockIdx.x * 256;
      P[pb + c]       = (double)s;
      P[pb + 128 + c] = (double)q;
    }
  }
}

// ---------------- fallback: direct edge MLP + naive atomics (unsorted) ----------------

__global__ __launch_bounds__(256) void k_msg_direct(const float* __restrict__ h,
                                                    const int* __restrict__ ei, const float* __restrict__ u,
                                                    const float* __restrict__ pos, const float* __restrict__ invd,
                                                    const float* __restrict__ W1, const float* __restrict__ b1,
                                                    const float* __restrict__ W2, const float* __restrict__ b2,
                                                    float* __restrict__ agg) {
  __shared__ float hd[32 * 129];
  __shared__ float hsr[32 * 129];
  __shared__ float m1s[32 * 129];
  __shared__ int lsrc[32];
  __shared__ int ldst[32];
  __shared__ float lf[32][4];
  int tid = threadIdx.x;
  int base = blockIdx.x * 32;
  if (tid < 32) {
    int e = base + tid;
    int s = ei[e], d = ei[NE + e];
    s = s < 0 ? 0 : (s >= NN ? NN - 1 : s);
    d = d < 0 ? 0 : (d >= NN ? NN - 1 : d);
    lsrc[tid] = s; ldst[tid] = d;
    lf[tid][0] = u[d] - u[s];
    lf[tid][1] = pos[d*3+1] - pos[s*3+1];
    lf[tid][2] = pos[d*3+2] - pos[s*3+2];
    lf[tid][3] = pos[d*3+0];
  }
  __syncthreads();
#pragma unroll
  for (int r = 0; r < 16; ++r) {
    int lin = r*256 + tid;
    int n = lin >> 7, j = lin & 127;
    hd[n*129 + j]  = h[(size_t)ldst[n]*HD + j];
    hsr[n*129 + j] = h[(size_t)lsrc[n]*HD + j];
  }
  __syncthreads();
  int el = tid & 31, jg = tid >> 5;
  float f0 = lf[el][0], f1 = lf[el][1], f2 = lf[el][2], f3 = lf[el][3];
  const float* We = W1 + 256*HD + (jg<<4);
  float acc[16];
#pragma unroll
  for (int q = 0; q < 4; ++q) {
    float4 w0 = *(const float4*)(We + 0*HD + (q<<2));
    float4 w1 = *(const float4*)(We + 1*HD + (q<<2));
    float4 w2 = *(const float4*)(We + 2*HD + (q<<2));
    float4 w3 = *(const float4*)(We + 3*HD + (q<<2));
    float4 bb = *(const float4*)(b1 + (jg<<4) + (q<<2));
    acc[q*4+0] = f0*w0.x + f1*w1.x + f2*w2.x + f3*w3.x + bb.x;
    acc[q*4+1] = f0*w0.y + f1*w1.y + f2*w2.y + f3*w3.y + bb.y;
    acc[q*4+2] = f0*w0.z + f1*w1.z + f2*w2.z + f3*w3.z + bb.z;
    acc[q*4+3] = f0*w0.w + f1*w1.w + f2*w2.w + f3*w3.w + bb.w;
  }
  for (int k = 0; k < HD; ++k) {
    float a  = hd[el*129 + k];
    float bs = hsr[el*129 + k];
    const float4* wa = (const float4*)(W1 + (size_t)k*HD + (jg<<4));
    const float4* wb = (const float4*)(W1 + (size_t)(128 + k)*HD + (jg<<4));
#pragma unroll
    for (int q = 0; q < 4; ++q) {
      float4 w1v = wa[q];
      float4 w2v = wb[q];
      acc[q*4+0] = fmaf(a, w1v.x, fmaf(bs, w2v.x, acc[q*4+0]));
      acc[q*4+1] = fmaf(a, w1v.y, fmaf(bs, w2v.y, acc[q*4+1]));
      acc[q*4+2] = fmaf(a, w1v.z, fmaf(bs, w2v.z, acc[q*4+2]));
      acc[q*4+3] = fmaf(a, w1v.w, fmaf(bs, w2v.w, acc[q*4+3]));
    }
  }
#pragma unroll
  for (int i = 0; i < 16; ++i) m1s[el*129 + (jg<<4) + i] = fmaxf(acc[i], 0.f);
  __syncthreads();
  float acc2[16];
#pragma unroll
  for (int q = 0; q < 4; ++q) {
    float4 bb = *(const float4*)(b2 + (jg<<4) + (q<<2));
    acc2[q*4+0] = bb.x; acc2[q*4+1] = bb.y; acc2[q*4+2] = bb.z; acc2[q*4+3] = bb.w;
  }
  for (int k = 0; k < HD; ++k) {
    float a = m1s[el*129 + k];
    const float4* wp = (const float4*)(W2 + (size_t)k*HD + (jg<<4));
#pragma unroll
    for (int q = 0; q < 4; ++q) {
      float4 wv = wp[q];
      acc2[q*4+0] = fmaf(a, wv.x, acc2[q*4+0]);
      acc2[q*4+1] = fmaf(a, wv.y, acc2[q*4+1]);
      acc2[q*4+2] = fmaf(a, wv.z, acc2[q*4+2]);
      acc2[q*4+3] = fmaf(a, wv.w, acc2[q*4+3]);
    }
  }
#pragma unroll
  for (int i = 0; i < 16; ++i) hd[el*129 + (jg<<4) + i] = fmaxf(acc2[i], 0.f);
  __syncthreads();
  if (tid < HD) {
    int j = tid;
    for (int e = 0; e < 32; ++e) {
      int de = ldst[e];
      atomicAdd(&agg[(size_t)de*HD + j], hd[e*129 + j] * invd[de]);
    }
  }
}

// ---------------- fallback node update MLP (fp32) ----------------

__global__ __launch_bounds__(256) void k_upd(float* __restrict__ h, const float* __restrict__ agg,
                                             const float* __restrict__ pos,
                                             const float* __restrict__ W1, const float* __restrict__ b1,
                                             const float* __restrict__ W2, const float* __restrict__ b2,
                                             double* __restrict__ stats) {
  __shared__ float hs[32 * 129];
  __shared__ float as_[32 * 129];
  int tid = threadIdx.x;
  int base = blockIdx.x * 32;
#pragma unroll
  for (int r = 0; r < 16; ++r) {
    int lin = r*256 + tid;
    int n = lin >> 7, j = lin & 127;
    int gn = base + n;
    hs[n*129 + j]  = (gn < NN) ? h[(size_t)gn*HD + j]   : 0.f;
    as_[n*129 + j] = (gn < NN) ? agg[(size_t)gn*HD + j] : 0.f;
  }
  __syncthreads();
  int nl = tid & 31, jg = tid >> 5;
  int gn = base + nl;
  float var = (gn < NN) ? pos[gn*3+0] : 0.f;
  float acc[16];
#pragma unroll
  for (int q = 0; q < 4; ++q) {
    int j = (jg<<4) + (q<<2);
    float4 bb = *(const float4*)(b1 + j);
    float4 wv = *(const float4*)(W1 + 256*HD + j);
    acc[q*4+0] = fmaf(var, wv.x, bb.x);
    acc[q*4+1] = fmaf(var, wv.y, bb.y);
    acc[q*4+2] = fmaf(var, wv.z, bb.z);
    acc[q*4+3] = fmaf(var, wv.w, bb.w);
  }
  for (int k = 0; k < HD; ++k) {
    float a = hs[nl*129 + k];
    float g = as_[nl*129 + k];
    const float4* w1p = (const float4*)(W1 + (size_t)k*HD + (jg<<4));
    const float4* w2p = (const float4*)(W1 + (size_t)(128 + k)*HD + (jg<<4));
#pragma unroll
    for (int q = 0; q < 4; ++q) {
      float4 wa = w1p[q];
      float4 wb = w2p[q];
      acc[q*4+0] = fmaf(a, wa.x, fmaf(g, wb.x, acc[q*4+0]));
      acc[q*4+1] = fmaf(a, wa.y, fmaf(g, wb.y, acc[q*4+1]));
      acc[q*4+2] = fmaf(a, wa.z, fmaf(g, wb.z, acc[q*4+2]));
      acc[q*4+3] = fmaf(a, wa.w, fmaf(g, wb.w, acc[q*4+3]));
    }
  }
  float up1[16];
#pragma unroll
  for (int i = 0; i < 16; ++i) up1[i] = fmaxf(acc[i], 0.f);
  __syncthreads();
#pragma unroll
  for (int i = 0; i < 16; ++i) as_[nl*129 + (jg<<4) + i] = up1[i];
  __syncthreads();
  float acc2[16];
#pragma unroll
  for (int q = 0; q < 4; ++q) {
    float4 bb = *(const float4*)(b2 + (jg<<4) + (q<<2));
    acc2[q*4+0] = bb.x; acc2[q*4+1] = bb.y; acc2[q*4+2] = bb.z; acc2[q*4+3] = bb.w;
  }
  for (int k = 0; k < HD; ++k) {
    float a = as_[nl*129 + k];
    const float4* wp = (const float4*)(W2 + (size_t)k*HD + (jg<<4));
#pragma unroll
    for (int q = 0; q < 4; ++q) {
      float4 wv = wp[q];
      acc2[q*4+0] = fmaf(a, wv.x, acc2[q*4+0]);
      acc2[q*4+1] = fmaf(a, wv.y, acc2[q*4+1]);
      acc2[q*4+2] = fmaf(a, wv.z, acc2[q*4+2]);
      acc2[q*4+3] = fmaf(a, wv.w, acc2[q*4+3]);
    }
  }
  float x[16];
#pragma unroll
  for (int i = 0; i < 16; ++i)
    x[i] = hs[nl*129 + (jg<<4) + i] + fmaxf(acc2[i], 0.f);
  if (gn < NN) {
#pragma unroll
    for (int q = 0; q < 4; ++q)
      *(float4*)(h + (size_t)gn*HD + (jg<<4) + (q<<2)) = make_float4(x[q*4+0], x[q*4+1], x[q*4+2], x[q*4+3]);
  }
  __syncthreads();
#pragma unroll
  for (int i = 0; i < 16; ++i) hs[nl*129 + (jg<<4) + i] = (gn < NN) ? x[i] : 0.f;
  __syncthreads();
  if (tid < HD) {
    double s = 0.0, sq = 0.0;
    for (int e = 0; e < 32; ++e) { double v = (double)hs[e*129 + tid]; s += v; sq += v*v; }
    atomicAdd(&stats[tid], s);
    atomicAdd(&stats[HD + tid], sq);
  }
}

// ---------------- CNN head (optional fused BN of last layer) ----------------

__global__ __launch_bounds__(256) void k_conv(const float* __restrict__ h,
                                              const float* __restrict__ musig,
                                              const float* __restrict__ g, const float* __restrict__ be,
                                              int applyBN,
                                              const float* __restrict__ c1W, const float* __restrict__ c1b,
                                              const float* __restrict__ c2W, const float* __restrict__ c2b,
                                              const float* __restrict__ c3W, const float* __restrict__ c3b,
                                              float* __restrict__ out) {
  __shared__ float xs[4][128];
  __shared__ float o1[4][152];
  __shared__ float o2[4][72];
  int tid = threadIdx.x;
  int w = tid >> 6, lane = tid & 63;
  int n = blockIdx.x * 4 + w;
#pragma unroll
  for (int half = 0; half < 2; ++half) {
    int j = half * 64 + lane;
    float v = h[(size_t)n*HD + j];
    if (applyBN) v = g[j] * (v - musig[j]) * musig[HD + j] + be[j];
    xs[w][j] = v;
  }
  __syncthreads();
  for (int o = lane; o < 152; o += 64) {
    int oc = o / 38, t = o % 38;
    float s = c1b[oc];
#pragma unroll
    for (int k = 0; k < 16; ++k) s = fmaf(xs[w][t*3 + k], c1W[oc*16 + k], s);
    o1[w][oc*38 + t] = fmaxf(s, 0.f);
  }
  __syncthreads();
  for (int o = lane; o < 72; o += 64) {
    int oc = o / 9, t = o % 9;
    float s = c2b[oc];
    for (int ic = 0; ic < 4; ++ic) {
#pragma unroll
      for (int k = 0; k < 12; ++k) s = fmaf(o1[w][ic*38 + t*3 + k], c2W[oc*48 + ic*12 + k], s);
    }
    o2[w][oc*9 + t] = fmaxf(s, 0.f);
  }
  __syncthreads();
  int ic = lane >> 3, k = lane & 7;
  float t3 = o2[w][ic*9 + k] * c3W[ic*8 + k];
  for (int off = 32; off; off >>= 1) t3 += __shfl_down(t3, off);
  if (lane == 0) out[n] = 0.001f * (t3 + c3b[0]);
}

// ---------------- launcher ----------------

extern "C" void kernel_launch(void* const* d_in, const int* in_sizes, int n_in,
                              void* d_out, int out_size, void* d_ws, size_t ws_size,
                              hipStream_t stream) {
  (void)out_size;
  float* out = (float*)d_out;

  static const int expect[27] = {
    50000, 150000, 1200000,
    512, 128, 128, 128,
    16384, 128, 128, 128,
    199680, 768, 98304, 768, 197376, 768, 98304, 768,
    768, 768,
    64, 4, 384, 8, 64, 1
  };
  if (n_in != 27) { k_code<<<1, 64, 0, stream>>>(out, 5000099.f); return; }
  for (int i = 0; i < 27; ++i)
    if (in_sizes[i] != expect[i]) { k_code<<<1, 64, 0, stream>>>(out, 5000100.f + (float)i); return; }

  const float* u    = (const float*)d_in[0];
  const float* pos  = (const float*)d_in[1];
  const int*   ei   = (const int*)d_in[2];
  const float* eW1  = (const float*)d_in[3];
  const float* eb1  = (const float*)d_in[4];
  const float* eg1  = (const float*)d_in[5];
  const float* ebe1 = (const float*)d_in[6];
  const float* eW2  = (const float*)d_in[7];
  const float* eb2  = (const float*)d_in[8];
  const float* eg2  = (const float*)d_in[9];
  const float* ebe2 = (const float*)d_in[10];
  const float* m1W  = (const float*)d_in[11];
  const float* m1b  = (const float*)d_in[12];
  const float* m2W  = (const float*)d_in[13];
  const float* m2b  = (const float*)d_in[14];
  const float* u1W  = (const float*)d_in[15];
  const float* u1b  = (const float*)d_in[16];
  const float* u2W  = (const float*)d_in[17];
  const float* u2b  = (const float*)d_in[18];
  const float* bng  = (const float*)d_in[19];
  const float* bnb  = (const float*)d_in[20];
  const float* c1W  = (const float*)d_in[21];
  const float* c1b  = (const float*)d_in[22];
  const float* c2W  = (const float*)d_in[23];
  const float* c2b  = (const float*)d_in[24];
  const float* c3W  = (const float*)d_in[25];
  const float* c3b  = (const float*)d_in[26];

  // ---- workspace ----
  char* wsp = (char*)d_ws;
  size_t off = 0;
  auto alloc = [&](size_t bytes) -> void* {
    void* p = wsp + off;
    off = (off + bytes + 255) & ~(size_t)255;
    return p;
  };
  double* stats  = (double*)alloc(256 * 8);
  float*  musig  = (float*)alloc(256 * 4);
  int*    deg    = (int*)alloc((size_t)NN * 4);
  int*    cursor = (int*)alloc((size_t)NN * 4);
  int*    blk    = (int*)alloc(256 * 4);
  float*  invd   = (float*)alloc((size_t)NN * 4);
  float*  h      = (float*)alloc((size_t)NN * HD * 4);
  float*  agg    = (float*)alloc((size_t)NN * HD * 4);
  double* P      = (double*)alloc((size_t)3200 * 256 * 8);
  size_t needed_direct = off;
  unsigned short* A = (unsigned short*)alloc((size_t)NN * HD * 2);
  unsigned short* B = (unsigned short*)alloc((size_t)NN * HD * 2);
  float*  sfeat  = (float*)alloc((size_t)NE * 4 * 4);
  int*    ssrc   = (int*)alloc((size_t)NE * 4);
  int*    sdst   = (int*)alloc((size_t)NE * 4);
  int*    rowstart = (int*)alloc((size_t)(NN + 1) * 4);
  unsigned short* w2t = (unsigned short*)alloc((size_t)NL * HD * HD * 2);
  unsigned short* u2t = (unsigned short*)alloc((size_t)NL * HD * HD * 2);
  unsigned short* u1t = (unsigned short*)alloc((size_t)NL * HD * 256 * 2);
  unsigned short* abt = (unsigned short*)alloc((size_t)NL * 256 * HD * 2);
  size_t needed_fast = off;

  if (ws_size < needed_direct) {
    k_code<<<1, 64, 0, stream>>>(out, (float)(9000000u + (unsigned)(ws_size >> 20)));
    return;
  }
  const bool fast = (ws_size >= needed_fast);

  const int nbN  = (NN + 255) / 256;
  const int nbE  = (NE + 255) / 256;
  const int nt32 = (NN + 31) / 32;
  const int nbBN = NN * HD / 256;
  const int nbMU = NN / DPB;   // 3125 blocks x 16 dsts

  // ---- degree / inverse degree (+ sort + bf16 weight transposes if fast) ----
  hipMemsetAsync(deg, 0, (size_t)NN * 4, stream);
  k_deg<<<nbE, 256, 0, stream>>>(ei, deg);
  k_scan1<<<nbN, 256, 0, stream>>>(deg, cursor, blk, invd);
  if (fast) {
    k_scan2<<<1, 256, 0, stream>>>(blk, nbN);
    k_scan3<<<nbN, 256, 0, stream>>>(cursor, blk, rowstart);
    k_scatter<<<nbE, 256, 0, stream>>>(ei, u, pos, cursor, ssrc, sdst, sfeat);
    k_w2t<<<(NL*HD*HD + 255) / 256, 256, 0, stream>>>(m2W, w2t);
    k_w2t<<<(NL*HD*HD + 255) / 256, 256, 0, stream>>>(u2W, u2t);
    k_u1t<<<(NL*HD*256 + 255) / 256, 256, 0, stream>>>(u1W, u1t);
    k_abt<<<(NL*256*HD + 255) / 256, 256, 0, stream>>>(m1W, abt);
  }

  // ---- embedding (partial-stats path) ----
  k_emb1<<<nt32, 256, 0, stream>>>(u, pos, eW1, eb1, h, P);
  k_redP<<<128, 256, 0, stream>>>(P, nt32, musig);
  k_bn<<<nbBN, 256, 0, stream>>>(h, musig, eg1, ebe1, 1);
  k_emb2<<<nt32, 256, 0, stream>>>(h, eW2, eb2, P);
  k_redP<<<128, 256, 0, stream>>>(P, nt32, musig);
  k_bn<<<nbBN, 256, 0, stream>>>(h, musig, eg2, ebe2, 0);

  // ---- message-passing layers ----
  for (int i = 0; i < NL; ++i) {
    if (fast) {
      k_ab_mfma<<<nt32, 256, 0, stream>>>(h, abt + (size_t)i * 256 * HD,
                                          musig, bng + (size_t)(i > 0 ? i - 1 : 0) * HD,
                                          bnb + (size_t)(i > 0 ? i - 1 : 0) * HD,
                                          (i > 0) ? 1 : 0, A, B);
      k_msgupd<<<nbMU, 256, 0, stream>>>(A, B, ssrc, sdst, sfeat, invd, rowstart,
                                         m1W + (size_t)i * 260 * HD, m1b + (size_t)i * HD,
                                         w2t + (size_t)i * HD * HD, m2b + (size_t)i * HD,
                                         h, pos,
                                         u1t + (size_t)i * HD * 256,
                                         u1W + (size_t)i * 32896 + 256 * HD,
                                         u1b + (size_t)i * HD,
                                         u2t + (size_t)i * HD * HD,
                                         u2b + (size_t)i * HD, P);
      k_redP<<<128, 256, 0, stream>>>(P, nbMU, musig);
    } else {
      hipMemsetAsync(agg, 0, (size_t)NN * HD * 4, stream);
      k_msg_direct<<<NE / 32, 256, 0, stream>>>(h, ei, u, pos, invd,
                                                m1W + (size_t)i * 260 * HD, m1b + (size_t)i * HD,
                                                m2W + (size_t)i * HD * HD, m2b + (size_t)i * HD, agg);
      hipMemsetAsync(stats, 0, 256 * 8, stream);
      k_upd<<<nt32, 256, 0, stream>>>(h, agg, pos,
                                      u1W + (size_t)i * 257 * HD, u1b + (size_t)i * HD,
                                      u2W + (size_t)i * HD * HD, u2b + (size_t)i * HD, stats);
      k_redA<<<1, 128, 0, stream>>>(stats, musig);
      k_bn<<<nbBN, 256, 0, stream>>>(h, musig, bng + (size_t)i * HD, bnb + (size_t)i * HD, 0);
    }
  }

  // ---- CNN head (fused BN of layer 5 in fast path) ----
  k_conv<<<NN / 4, 256, 0, stream>>>(h, musig, bng + (size_t)(NL - 1) * HD, bnb + (size_t)(NL - 1) * HD,
                                     fast ? 1 : 0,
                                     c1W, c1b, c2W, c2b, c3W, c3b, out);
}

// Round 14
// 1498.165 us; speedup vs baseline: 1.4815x; 1.4815x over previous
//
#include <hip/hip_runtime.h>

#define NN 50000
#define NE 600000
#define HD 128
#define NL 6
#define DPB 16   // dsts per block (NN/DPB = 3125 exact)

typedef __attribute__((ext_vector_type(8))) short bf16x8;
typedef __attribute__((ext_vector_type(4))) float f32x4;

__device__ inline unsigned short f2bf(float x) {
  unsigned u = __float_as_uint(x);
  u += 0x7FFF + ((u >> 16) & 1);           // RNE on raw bits
  return (unsigned short)(u >> 16);
}
__device__ inline float bf2f(unsigned short s) {
  return __uint_as_float((unsigned)s << 16);
}
__device__ inline unsigned pk2(float a, float b) {
  return (unsigned)f2bf(a) | ((unsigned)f2bf(b) << 16);
}

__global__ void k_code(float* __restrict__ out, float code) {
  if (threadIdx.x == 0 && blockIdx.x == 0) out[0] = code;
}

// ---------------- weight transposes -> bf16 [layer][n][k] ----------------

__global__ __launch_bounds__(256) void k_w2t(const float* __restrict__ W, unsigned short* __restrict__ T) {
  int idx = blockIdx.x * 256 + threadIdx.x;
  if (idx >= NL * HD * HD) return;
  int l = idx >> 14, r = idx & 16383;
  int n = r >> 7, k = r & 127;
  T[idx] = f2bf(W[(l << 14) + (k << 7) + n]);
}

__global__ __launch_bounds__(256) void k_u1t(const float* __restrict__ W, unsigned short* __restrict__ T) {
  int idx = blockIdx.x * 256 + threadIdx.x;
  if (idx >= NL * 128 * 256) return;
  int l = idx >> 15, r = idx & 32767;
  int n = r >> 8, k = r & 255;
  T[idx] = f2bf(W[l * 32896 + k * 128 + n]);
}

__global__ __launch_bounds__(256) void k_abt(const float* __restrict__ W, unsigned short* __restrict__ T) {
  int idx = blockIdx.x * 256 + threadIdx.x;
  if (idx >= NL * 256 * 128) return;
  int l = idx >> 15, r = idx & 32767;
  int n = r >> 7, k = r & 127;
  int row = (n < 128) ? k : 128 + k;
  int col = n & 127;
  T[idx] = f2bf(W[l * 33280 + row * 128 + col]);
}

// ---------------- degree histogram, scan, counting sort (by dst) ----------------

__global__ __launch_bounds__(256) void k_deg(const int* __restrict__ ei, int* __restrict__ deg) {
  int e = blockIdx.x * 256 + threadIdx.x;
  if (e < NE) {
    int d = ei[NE + e];
    if (d >= 0 && d < NN) atomicAdd(&deg[d], 1);
  }
}

__global__ __launch_bounds__(256) void k_scan1(const int* __restrict__ deg, int* __restrict__ cursor,
                                               int* __restrict__ blk, float* __restrict__ invd) {
  __shared__ int sd[256];
  int t = threadIdx.x;
  int i = blockIdx.x * 256 + t;
  int v = (i < NN) ? deg[i] : 0;
  sd[t] = v;
  __syncthreads();
  for (int off = 1; off < 256; off <<= 1) {
    int x = (t >= off) ? sd[t - off] : 0;
    __syncthreads();
    if (t >= off) sd[t] += x;
    __syncthreads();
  }
  int incl = sd[t];
  if (i < NN) {
    cursor[i] = incl - v;
    invd[i] = 1.0f / fmaxf((float)v, 1.0f);
  }
  if (t == 255) blk[blockIdx.x] = incl;
}

__global__ __launch_bounds__(256) void k_scan2(int* __restrict__ blk, int nb) {
  __shared__ int sd[256];
  int t = threadIdx.x;
  int v = (t < nb) ? blk[t] : 0;
  sd[t] = v;
  __syncthreads();
  for (int off = 1; off < 256; off <<= 1) {
    int x = (t >= off) ? sd[t - off] : 0;
    __syncthreads();
    if (t >= off) sd[t] += x;
    __syncthreads();
  }
  if (t < nb) blk[t] = sd[t] - v;
}

__global__ __launch_bounds__(256) void k_scan3(int* __restrict__ cursor, const int* __restrict__ blk,
                                               int* __restrict__ rowstart) {
  int i = blockIdx.x * 256 + threadIdx.x;
  if (i < NN) {
    int v = cursor[i] + blk[blockIdx.x];
    cursor[i] = v;
    rowstart[i] = v;
  }
  if (i == 0) rowstart[NN] = NE;
}

__global__ __launch_bounds__(256) void k_scatter(const int* __restrict__ ei, const float* __restrict__ u,
                                                 const float* __restrict__ pos, int* __restrict__ cursor,
                                                 int* __restrict__ ssrc, int* __restrict__ sdst,
                                                 float* __restrict__ sfeat) {
  int e = blockIdx.x * 256 + threadIdx.x;
  if (e >= NE) return;
  int s = ei[e], d = ei[NE + e];
  s = s < 0 ? 0 : (s >= NN ? NN - 1 : s);
  d = d < 0 ? 0 : (d >= NN ? NN - 1 : d);
  int p = atomicAdd(&cursor[d], 1);
  ssrc[p] = s;
  sdst[p] = d;
  float du  = u[d] - u[s];
  float dpx = pos[d*3+1] - pos[s*3+1];
  float dpy = pos[d*3+2] - pos[s*3+2];
  float vi  = pos[d*3+0];
  ((float4*)sfeat)[p] = make_float4(du, dpx, dpy, vi);
}

// ---------------- embedding (per-block partial stats -> P) ----------------

__global__ __launch_bounds__(256) void k_emb1(const float* __restrict__ u, const float* __restrict__ pos,
                                              const float* __restrict__ W, const float* __restrict__ b,
                                              float* __restrict__ h, double* __restrict__ P) {
  __shared__ float xs[32 * 129];
  int tid = threadIdx.x;
  int nl = tid & 31, jg = tid >> 5;
  int gn = blockIdx.x * 32 + nl;
  float f0 = 0.f, f1 = 0.f, f2 = 0.f, f3 = 0.f;
  if (gn < NN) { f0 = u[gn]; f1 = pos[gn*3+1]; f2 = pos[gn*3+2]; f3 = pos[gn*3+0]; }
  float x[16];
#pragma unroll
  for (int q = 0; q < 4; ++q) {
    int j = (jg << 4) + (q << 2);
    float4 w0 = *(const float4*)(W + 0*HD + j);
    float4 w1 = *(const float4*)(W + 1*HD + j);
    float4 w2 = *(const float4*)(W + 2*HD + j);
    float4 w3 = *(const float4*)(W + 3*HD + j);
    float4 bb = *(const float4*)(b + j);
    x[q*4+0] = f0*w0.x + f1*w1.x + f2*w2.x + f3*w3.x + bb.x;
    x[q*4+1] = f0*w0.y + f1*w1.y + f2*w2.y + f3*w3.y + bb.y;
    x[q*4+2] = f0*w0.z + f1*w1.z + f2*w2.z + f3*w3.z + bb.z;
    x[q*4+3] = f0*w0.w + f1*w1.w + f2*w2.w + f3*w3.w + bb.w;
  }
  if (gn < NN) {
#pragma unroll
    for (int q = 0; q < 4; ++q)
      *(float4*)(h + (size_t)gn*HD + (jg<<4) + (q<<2)) = make_float4(x[q*4+0], x[q*4+1], x[q*4+2], x[q*4+3]);
  }
#pragma unroll
  for (int i = 0; i < 16; ++i) xs[nl*129 + (jg<<4) + i] = (gn < NN) ? x[i] : 0.f;
  __syncthreads();
  if (tid < HD) {
    double s = 0.0, sq = 0.0;
    for (int e = 0; e < 32; ++e) { double v = (double)xs[e*129 + tid]; s += v; sq += v*v; }
    size_t pb = (size_t)blockIdx.x * 256;
    P[pb + tid] = s;
    P[pb + 128 + tid] = sq;
  }
}

__global__ __launch_bounds__(256) void k_emb2(float* __restrict__ h, const float* __restrict__ W,
                                              const float* __restrict__ b, double* __restrict__ P) {
  __shared__ float hs[32 * 129];
  int tid = threadIdx.x;
  int base = blockIdx.x * 32;
#pragma unroll
  for (int r = 0; r < 16; ++r) {
    int lin = r*256 + tid;
    int n = lin >> 7, j = lin & 127;
    int gn = base + n;
    hs[n*129 + j] = (gn < NN) ? h[(size_t)gn*HD + j] : 0.f;
  }
  __syncthreads();
  int nl = tid & 31, jg = tid >> 5;
  int gn = base + nl;
  float acc[16];
#pragma unroll
  for (int q = 0; q < 4; ++q) {
    float4 bb = *(const float4*)(b + (jg<<4) + (q<<2));
    acc[q*4+0] = bb.x; acc[q*4+1] = bb.y; acc[q*4+2] = bb.z; acc[q*4+3] = bb.w;
  }
  for (int k = 0; k < HD; ++k) {
    float a = hs[nl*129 + k];
    const float4* wp = (const float4*)(W + (size_t)k*HD + (jg<<4));
#pragma unroll
    for (int q = 0; q < 4; ++q) {
      float4 wv = wp[q];
      acc[q*4+0] = fmaf(a, wv.x, acc[q*4+0]);
      acc[q*4+1] = fmaf(a, wv.y, acc[q*4+1]);
      acc[q*4+2] = fmaf(a, wv.z, acc[q*4+2]);
      acc[q*4+3] = fmaf(a, wv.w, acc[q*4+3]);
    }
  }
  if (gn < NN) {
#pragma unroll
    for (int q = 0; q < 4; ++q)
      *(float4*)(h + (size_t)gn*HD + (jg<<4) + (q<<2)) = make_float4(acc[q*4+0], acc[q*4+1], acc[q*4+2], acc[q*4+3]);
  }
  __syncthreads();
#pragma unroll
  for (int i = 0; i < 16; ++i) hs[nl*129 + (jg<<4) + i] = (gn < NN) ? acc[i] : 0.f;
  __syncthreads();
  if (tid < HD) {
    double s = 0.0, sq = 0.0;
    for (int e = 0; e < 32; ++e) { double v = (double)hs[e*129 + tid]; s += v; sq += v*v; }
    size_t pb = (size_t)blockIdx.x * 256;
    P[pb + tid] = s;
    P[pb + 128 + tid] = sq;
  }
}

// reduce P[nrows][256] -> musig (one block per channel)
__global__ __launch_bounds__(256) void k_redP(const double* __restrict__ P, int nrows,
                                              float* __restrict__ musig) {
  __shared__ double sd[256];
  __shared__ double sq_[256];
  int c = blockIdx.x;       // 0..127
  int t = threadIdx.x;
  double s = 0.0, q = 0.0;
  for (int k = t; k < nrows; k += 256) {
    s += P[(size_t)k*256 + c];
    q += P[(size_t)k*256 + 128 + c];
  }
  sd[t] = s; sq_[t] = q;
  __syncthreads();
  for (int off = 128; off; off >>= 1) {
    if (t < off) { sd[t] += sd[t + off]; sq_[t] += sq_[t + off]; }
    __syncthreads();
  }
  if (t == 0) {
    double mu  = sd[0] / (double)NN;
    double var = sq_[0] / (double)NN - mu * mu;
    musig[c]      = (float)mu;
    musig[HD + c] = (float)(1.0 / sqrt(var + 1e-5));
  }
}

__global__ void k_redA(const double* __restrict__ stats, float* __restrict__ musig) {
  int c = threadIdx.x;   // 128
  double mu  = stats[c] / (double)NN;
  double var = stats[128 + c] / (double)NN - mu * mu;
  musig[c]      = (float)mu;
  musig[HD + c] = (float)(1.0 / sqrt(var + 1e-5));
}

__global__ __launch_bounds__(256) void k_bn(float* __restrict__ h, const float* __restrict__ musig,
                                            const float* __restrict__ g, const float* __restrict__ be,
                                            int relu) {
  int idx = blockIdx.x * 256 + threadIdx.x;
  if (idx >= NN * HD) return;
  int j = idx & 127;
  float x = h[idx];
  x = g[j] * (x - musig[j]) * musig[HD + j] + be[j];
  if (relu) x = fmaxf(x, 0.f);
  h[idx] = x;
}

// ---------------- k_ab via MFMA, fused BN of previous layer, bf16 A/B output ----------------

__global__ __launch_bounds__(256) void k_ab_mfma(float* __restrict__ h,
                                                 const unsigned short* __restrict__ abt,
                                                 const float* __restrict__ musig,
                                                 const float* __restrict__ g, const float* __restrict__ be,
                                                 int applyBN,
                                                 unsigned short* __restrict__ A, unsigned short* __restrict__ B) {
  __shared__ unsigned short hbf[32 * 136];
  int tid = threadIdx.x;
  int base = blockIdx.x * 32;
#pragma unroll
  for (int r = 0; r < 16; ++r) {
    int lin = r*256 + tid;
    int n = lin >> 7, j = lin & 127;
    int gn = base + n;
    float hv = (gn < NN) ? h[(size_t)gn*HD + j] : 0.f;
    if (applyBN) {
      hv = g[j] * (hv - musig[j]) * musig[HD + j] + be[j];
      if (gn < NN) h[(size_t)gn*HD + j] = hv;
    }
    hbf[n*136 + j] = f2bf((gn < NN) ? hv : 0.f);
  }
  __syncthreads();
  int wv = tid >> 6, lane = tid & 63;
  int quad = lane >> 4, mrow = lane & 15;
  int mt = wv & 1, ntg = wv >> 1;
  f32x4 acc[8];
#pragma unroll
  for (int t = 0; t < 8; ++t) acc[t] = (f32x4){0.f,0.f,0.f,0.f};
#pragma unroll
  for (int ks = 0; ks < 4; ++ks) {
    bf16x8 a = *(const bf16x8*)(hbf + (mt*16 + mrow)*136 + ks*32 + quad*8);
#pragma unroll
    for (int t = 0; t < 8; ++t) {
      bf16x8 b = *(const bf16x8*)(abt + (size_t)((ntg*8 + t)*16 + mrow)*128 + ks*32 + quad*8);
      acc[t] = __builtin_amdgcn_mfma_f32_16x16x32_bf16(a, b, acc[t], 0, 0, 0);
    }
  }
#pragma unroll
  for (int t = 0; t < 8; ++t) {
    int c = (ntg*8 + t)*16 + mrow;
#pragma unroll
    for (int r = 0; r < 4; ++r) {
      int gn = base + mt*16 + quad*4 + r;
      if (gn < NN) {
        if (c < 128) A[(size_t)gn*HD + c]       = f2bf(acc[t][r]);
        else         B[(size_t)gn*HD + c - 128] = f2bf(acc[t][r]);
      }
    }
  }
}

// ---------------- FUSED per-dst-block message + aggregate + node-update ----------------
// R10 structure (16 dsts/block, 3125 blocks, launch_bounds(256,2)); 32-edge chunks;
// meta prefetch 2 ahead, B-gather 1 ahead. ONE barrier per chunk: m1bf double-buffered;
// phase 2 split by COLUMNS (each wave: all 32 edges x its 2 col-tiles); m2 C-frag ->
// selection B-frag via intra-wave shuffles (no m2bf LDS, no bar2, no stride-40 conflicts).

__global__ __launch_bounds__(256, 2) void k_msgupd(const unsigned short* __restrict__ A,
                                                   const unsigned short* __restrict__ B,
                                                   const int* __restrict__ ssrc, const int* __restrict__ sdst,
                                                   const float* __restrict__ sfeat, const float* __restrict__ invd,
                                                   const int* __restrict__ rowstart,
                                                   const float* __restrict__ W1, const float* __restrict__ b1,
                                                   const unsigned short* __restrict__ w2t, const float* __restrict__ b2,
                                                   float* __restrict__ h, const float* __restrict__ pos,
                                                   const unsigned short* __restrict__ u1t,
                                                   const float* __restrict__ U1var, const float* __restrict__ ub1,
                                                   const unsigned short* __restrict__ u2t, const float* __restrict__ ub2,
                                                   double* __restrict__ P) {
  // smAB: As[16*136] | m1bf dbuf 2x[32*136]  (21760 B)
  // epilogue aliases: abf[16][264] @0 (8448 B), u1bf[16][136] @ +16*264 shorts
  __shared__ __align__(16) unsigned short smAB[16*136 + 2*32*136];
  __shared__ float wes[6 * 128];     // W1-edge rows 0-3, b1, b2
  __shared__ int ldstD[64];          // dbuf dst-local ids (999 = invalid)

  unsigned short* As   = smAB;
  unsigned short* m1b0 = smAB + 16*136;
  unsigned short* abf  = smAB;                 // epilogue alias [16][264]
  unsigned short* u1bf = smAB + 16*264;        // epilogue alias [16][136]

  int tid = threadIdx.x;
  int base = blockIdx.x * DPB;

  // ---- phase 0: stage As (16x128 bf16), weights ----
  {
    int row = tid >> 4, c16 = tid & 15;
    int gn = base + row;
    bf16x8 v = (bf16x8){0,0,0,0,0,0,0,0};
    if (gn < NN) v = *(const bf16x8*)(A + (size_t)gn*HD + c16*8);
    *(bf16x8*)(As + row*136 + c16*8) = v;
  }
  for (int i = tid; i < 768; i += 256) {
    int k = i >> 7, j = i & 127;
    float v;
    if (k < 4)       v = W1[(size_t)(256 + k)*HD + j];
    else if (k == 4) v = b1[j];
    else             v = b2[j];
    wes[i] = v;
  }
  int rs0 = rowstart[base];
  int rs1 = rowstart[base + DPB];
  __syncthreads();

  int wv = tid >> 6, lane = tid & 63;
  int quad = lane >> 4, mrow = lane & 15;
  int el = tid & 31, jg = tid >> 5;

  float b2c[2];
#pragma unroll
  for (int t = 0; t < 2; ++t) b2c[t] = wes[5*128 + (wv*2 + t)*16 + mrow];

  const float4* sf4 = (const float4*)sfeat;
  int nch = (rs1 - rs0 + 31) >> 5;

  f32x4 agg[2];
  agg[0] = (f32x4){0.f,0.f,0.f,0.f}; agg[1] = agg[0];

  // ---- prologue: meta(0), meta(1); B(0) ----
  int d_c; float4 f_c;
  int s_n1, d_n1; float4 f_n1;
  {
    int e = rs0 + el; bool v = e < rs1;
    int sc = v ? ssrc[e] : 0;
    d_c = v ? (sdst[e] - base) : 999;
    f_c = v ? sf4[e] : make_float4(0.f, 0.f, 0.f, 0.f);
    s_n1 = sc;
  }
  bf16x8 b0_c = *(const bf16x8*)(B + (size_t)s_n1*HD + (jg<<4));
  bf16x8 b1_c = *(const bf16x8*)(B + (size_t)s_n1*HD + (jg<<4) + 8);
  {
    int e = rs0 + 32 + el; bool v = e < rs1;
    s_n1 = v ? ssrc[e] : 0;
    d_n1 = v ? (sdst[e] - base) : 999;
    f_n1 = v ? sf4[e] : make_float4(0.f, 0.f, 0.f, 0.f);
  }

  int par = 0;
  for (int ch = 0; ch < nch; ++ch) {
    int e0 = rs0 + ch*32;
    // issue meta(ch+2)
    int s_n2, d_n2; float4 f_n2;
    {
      int e = e0 + 64 + el; bool v = e < rs1;
      s_n2 = v ? ssrc[e] : 0;
      d_n2 = v ? (sdst[e] - base) : 999;
      f_n2 = v ? sf4[e] : make_float4(0.f, 0.f, 0.f, 0.f);
    }
    // issue B(ch+1) now -> m1 covers its latency
    bf16x8 b0_n = *(const bf16x8*)(B + (size_t)s_n1*HD + (jg<<4));
    bf16x8 b1_n = *(const bf16x8*)(B + (size_t)s_n1*HD + (jg<<4) + 8);

    if (tid < 32) ldstD[par*32 + tid] = d_c;
    unsigned short* m1bf = m1b0 + par*32*136;

    // ---- phase 1: m1 -> m1bf[par] ----
    {
      int dA = (d_c < DPB) ? d_c : 0;
      float f0 = f_c.x, f1 = f_c.y, f2 = f_c.z, f3 = f_c.w;
      const unsigned short* Ar = As + dA*136 + (jg<<4);
      bf16x8 a0 = *(const bf16x8*)(Ar);
      bf16x8 a1 = *(const bf16x8*)(Ar + 8);
      float m1v[16];
#pragma unroll
      for (int q = 0; q < 4; ++q) {
        float4 w0 = *(const float4*)(wes + 0*128 + (jg<<4) + (q<<2));
        float4 w1 = *(const float4*)(wes + 1*128 + (jg<<4) + (q<<2));
        float4 w2 = *(const float4*)(wes + 2*128 + (jg<<4) + (q<<2));
        float4 w3 = *(const float4*)(wes + 3*128 + (jg<<4) + (q<<2));
        float4 bb = *(const float4*)(wes + 4*128 + (jg<<4) + (q<<2));
#pragma unroll
        for (int z = 0; z < 4; ++z) {
          int i = q*4 + z;
          unsigned short avs = (i < 8) ? (unsigned short)a0[i] : (unsigned short)a1[i-8];
          unsigned short bvs = (i < 8) ? (unsigned short)b0_c[i] : (unsigned short)b1_c[i-8];
          float we  = (z==0?w0.x:(z==1?w0.y:(z==2?w0.z:w0.w)));
          float w1e = (z==0?w1.x:(z==1?w1.y:(z==2?w1.z:w1.w)));
          float w2e = (z==0?w2.x:(z==1?w2.y:(z==2?w2.z:w2.w)));
          float w3e = (z==0?w3.x:(z==1?w3.y:(z==2?w3.z:w3.w)));
          float bbe = (z==0?bb.x:(z==1?bb.y:(z==2?bb.z:bb.w)));
          m1v[i] = fmaxf(bf2f(avs) + bf2f(bvs) + f0*we + f1*w1e + f2*w2e + f3*w3e + bbe, 0.f);
        }
      }
      unsigned* pp = (unsigned*)(m1bf + el*136 + (jg<<4));
#pragma unroll
      for (int i = 0; i < 8; ++i)
        pp[i] = pk2(m1v[2*i], m1v[2*i+1]);
    }
    __syncthreads();   // the ONLY barrier per chunk

    // ---- phase 2: m2 for ALL 32 edges x this wave's 2 col-tiles ----
    {
      f32x4 acc[2][2];
      acc[0][0] = (f32x4){0.f,0.f,0.f,0.f}; acc[0][1] = acc[0][0];
      acc[1][0] = acc[0][0]; acc[1][1] = acc[0][0];
#pragma unroll
      for (int ks = 0; ks < 4; ++ks) {
        bf16x8 a0 = *(const bf16x8*)(m1bf + (mrow)*136      + ks*32 + quad*8);
        bf16x8 a1 = *(const bf16x8*)(m1bf + (16 + mrow)*136 + ks*32 + quad*8);
#pragma unroll
        for (int t = 0; t < 2; ++t) {
          bf16x8 b = *(const bf16x8*)(w2t + (size_t)((wv*2 + t)*16 + mrow)*128 + ks*32 + quad*8);
          acc[0][t] = __builtin_amdgcn_mfma_f32_16x16x32_bf16(a0, b, acc[0][t], 0, 0, 0);
          acc[1][t] = __builtin_amdgcn_mfma_f32_16x16x32_bf16(a1, b, acc[1][t], 0, 0, 0);
        }
      }

      // selection A-frag: sel[m=dst=mrow][k=edge=quad*8+i]
      bf16x8 sel;
#pragma unroll
      for (int i = 0; i < 8; ++i) {
        int dl = ldstD[par*32 + quad*8 + i];
        sel[i] = (short)((dl == mrow) ? 0x3F80 : 0);
      }

      // intra-wave shuffle transpose: C-frag(edge rows) -> B-frag(edge k)
      int src0 = ((quad & 1) * 2) * 16 + mrow;
      int src1 = src0 + 16;
      bool useE0 = (quad < 2);
#pragma unroll
      for (int t = 0; t < 2; ++t) {
        float bb = b2c[t];
        unsigned p00 = pk2(fmaxf(acc[0][t][0] + bb, 0.f), fmaxf(acc[0][t][1] + bb, 0.f));
        unsigned p01 = pk2(fmaxf(acc[0][t][2] + bb, 0.f), fmaxf(acc[0][t][3] + bb, 0.f));
        unsigned p10 = pk2(fmaxf(acc[1][t][0] + bb, 0.f), fmaxf(acc[1][t][1] + bb, 0.f));
        unsigned p11 = pk2(fmaxf(acc[1][t][2] + bb, 0.f), fmaxf(acc[1][t][3] + bb, 0.f));
        unsigned a00 = (unsigned)__shfl((int)p00, src0);
        unsigned a01 = (unsigned)__shfl((int)p01, src0);
        unsigned a02 = (unsigned)__shfl((int)p00, src1);
        unsigned a03 = (unsigned)__shfl((int)p01, src1);
        unsigned e10 = (unsigned)__shfl((int)p10, src0);
        unsigned e11 = (unsigned)__shfl((int)p11, src0);
        unsigned e12 = (unsigned)__shfl((int)p10, src1);
        unsigned e13 = (unsigned)__shfl((int)p11, src1);
        bf16x8 bfr;
        unsigned* bp = (unsigned*)&bfr;
        bp[0] = useE0 ? a00 : e10;
        bp[1] = useE0 ? a01 : e11;
        bp[2] = useE0 ? a02 : e12;
        bp[3] = useE0 ? a03 : e13;
        agg[t] = __builtin_amdgcn_mfma_f32_16x16x32_bf16(sel, bfr, agg[t], 0, 0, 0);
      }
    }

    // shift pipeline
    d_c = d_n1; f_c = f_n1;
    s_n1 = s_n2; d_n1 = d_n2; f_n1 = f_n2;
    b0_c = b0_n; b1_c = b1_n;
    par ^= 1;
  }
  __syncthreads();   // protect abf overlay vs last chunk's m1bf reads

  // ================= fused 16-row update MLP =================
  // stage h (bf16) -> abf cols 0..127
  {
    int row = tid >> 4, c16 = tid & 15;
    int gn = base + row;   // always < NN
    float4 h0 = *(const float4*)(h + (size_t)gn*HD + c16*8);
    float4 h1 = *(const float4*)(h + (size_t)gn*HD + c16*8 + 4);
    unsigned* q = (unsigned*)(abf + row*264 + c16*8);
    q[0] = pk2(h0.x, h0.y); q[1] = pk2(h0.z, h0.w);
    q[2] = pk2(h1.x, h1.y); q[3] = pk2(h1.z, h1.w);
  }
  // stage agg*invd -> abf cols 128..255 (each wave owns its 2 col-tiles)
  {
    float invdv[4];
#pragma unroll
    for (int r = 0; r < 4; ++r) invdv[r] = invd[base + quad*4 + r];
#pragma unroll
    for (int t = 0; t < 2; ++t) {
      int c = (wv*2 + t)*16 + mrow;
#pragma unroll
      for (int r = 0; r < 4; ++r)
        abf[(quad*4 + r)*264 + 128 + c] = f2bf(agg[t][r] * invdv[r]);
    }
  }
  __syncthreads();   // abf ready

  int lo = mrow;
  float ub1c[2], uvarc[2], ub2c[2];
#pragma unroll
  for (int t = 0; t < 2; ++t) {
    int c = (wv*2 + t)*16 + lo;
    ub1c[t] = ub1[c]; uvarc[t] = U1var[c]; ub2c[t] = ub2[c];
  }
  float lvarv[4];
#pragma unroll
  for (int r = 0; r < 4; ++r) lvarv[r] = pos[(size_t)(base + quad*4 + r)*3 + 0];

  // u1: [h|agg] (16x256) @ u1t -> relu -> u1bf
  f32x4 ua[2];
  ua[0] = (f32x4){0.f,0.f,0.f,0.f}; ua[1] = ua[0];
#pragma unroll
  for (int ks = 0; ks < 8; ++ks) {
    bf16x8 a = *(const bf16x8*)(abf + lo*264 + ks*32 + quad*8);
#pragma unroll
    for (int t = 0; t < 2; ++t) {
      bf16x8 b = *(const bf16x8*)(u1t + (size_t)((wv*2 + t)*16 + lo)*256 + ks*32 + quad*8);
      ua[t] = __builtin_amdgcn_mfma_f32_16x16x32_bf16(a, b, ua[t], 0, 0, 0);
    }
  }
#pragma unroll
  for (int t = 0; t < 2; ++t) {
    int c = (wv*2 + t)*16 + lo;
#pragma unroll
    for (int r = 0; r < 4; ++r) {
      float v = fmaxf(ua[t][r] + ub1c[t] + lvarv[r]*uvarc[t], 0.f);
      u1bf[(quad*4 + r)*136 + c] = f2bf(v);
    }
  }
  __syncthreads();   // u1bf ready

  // u2: u1 (16x128) @ u2t
  f32x4 va[2];
  va[0] = (f32x4){0.f,0.f,0.f,0.f}; va[1] = va[0];
#pragma unroll
  for (int ks = 0; ks < 4; ++ks) {
    bf16x8 a = *(const bf16x8*)(u1bf + lo*136 + ks*32 + quad*8);
#pragma unroll
    for (int t = 0; t < 2; ++t) {
      bf16x8 b = *(const bf16x8*)(u2t + (size_t)((wv*2 + t)*16 + lo)*128 + ks*32 + quad*8);
      va[t] = __builtin_amdgcn_mfma_f32_16x16x32_bf16(a, b, va[t], 0, 0, 0);
    }
  }

  // residual + h write + BN partial stats -> P
#pragma unroll
  for (int t = 0; t < 2; ++t) {
    int c = (wv*2 + t)*16 + lo;
    float s = 0.f, q = 0.f;
#pragma unroll
    for (int r = 0; r < 4; ++r) {
      int gn = base + quad*4 + r;   // always < NN
      float x = h[(size_t)gn*HD + c] + fmaxf(va[t][r] + ub2c[t], 0.f);
      h[(size_t)gn*HD + c] = x;
      s += x; q += x*x;
    }
    s += __shfl_xor(s, 16); q += __shfl_xor(q, 16);
    s += __shfl_xor(s, 32); q += __shfl_xor(q, 32);
    if (quad == 0) {
      size_t pb = (size_t)blockIdx.x * 256;
      P[pb + c]       = (double)s;
      P[pb + 128 + c] = (double)q;
    }
  }
}

// ---------------- fallback: direct edge MLP + naive atomics (unsorted) ----------------

__global__ __launch_bounds__(256) void k_msg_direct(const float* __restrict__ h,
                                                    const int* __restrict__ ei, const float* __restrict__ u,
                                                    const float* __restrict__ pos, const float* __restrict__ invd,
                                                    const float* __restrict__ W1, const float* __restrict__ b1,
                                                    const float* __restrict__ W2, const float* __restrict__ b2,
                                                    float* __restrict__ agg) {
  __shared__ float hd[32 * 129];
  __shared__ float hsr[32 * 129];
  __shared__ float m1s[32 * 129];
  __shared__ int lsrc[32];
  __shared__ int ldst[32];
  __shared__ float lf[32][4];
  int tid = threadIdx.x;
  int base = blockIdx.x * 32;
  if (tid < 32) {
    int e = base + tid;
    int s = ei[e], d = ei[NE + e];
    s = s < 0 ? 0 : (s >= NN ? NN - 1 : s);
    d = d < 0 ? 0 : (d >= NN ? NN - 1 : d);
    lsrc[tid] = s; ldst[tid] = d;
    lf[tid][0] = u[d] - u[s];
    lf[tid][1] = pos[d*3+1] - pos[s*3+1];
    lf[tid][2] = pos[d*3+2] - pos[s*3+2];
    lf[tid][3] = pos[d*3+0];
  }
  __syncthreads();
#pragma unroll
  for (int r = 0; r < 16; ++r) {
    int lin = r*256 + tid;
    int n = lin >> 7, j = lin & 127;
    hd[n*129 + j]  = h[(size_t)ldst[n]*HD + j];
    hsr[n*129 + j] = h[(size_t)lsrc[n]*HD + j];
  }
  __syncthreads();
  int el = tid & 31, jg = tid >> 5;
  float f0 = lf[el][0], f1 = lf[el][1], f2 = lf[el][2], f3 = lf[el][3];
  const float* We = W1 + 256*HD + (jg<<4);
  float acc[16];
#pragma unroll
  for (int q = 0; q < 4; ++q) {
    float4 w0 = *(const float4*)(We + 0*HD + (q<<2));
    float4 w1 = *(const float4*)(We + 1*HD + (q<<2));
    float4 w2 = *(const float4*)(We + 2*HD + (q<<2));
    float4 w3 = *(const float4*)(We + 3*HD + (q<<2));
    float4 bb = *(const float4*)(b1 + (jg<<4) + (q<<2));
    acc[q*4+0] = f0*w0.x + f1*w1.x + f2*w2.x + f3*w3.x + bb.x;
    acc[q*4+1] = f0*w0.y + f1*w1.y + f2*w2.y + f3*w3.y + bb.y;
    acc[q*4+2] = f0*w0.z + f1*w1.z + f2*w2.z + f3*w3.z + bb.z;
    acc[q*4+3] = f0*w0.w + f1*w1.w + f2*w2.w + f3*w3.w + bb.w;
  }
  for (int k = 0; k < HD; ++k) {
    float a  = hd[el*129 + k];
    float bs = hsr[el*129 + k];
    const float4* wa = (const float4*)(W1 + (size_t)k*HD + (jg<<4));
    const float4* wb = (const float4*)(W1 + (size_t)(128 + k)*HD + (jg<<4));
#pragma unroll
    for (int q = 0; q < 4; ++q) {
      float4 w1v = wa[q];
      float4 w2v = wb[q];
      acc[q*4+0] = fmaf(a, w1v.x, fmaf(bs, w2v.x, acc[q*4+0]));
      acc[q*4+1] = fmaf(a, w1v.y, fmaf(bs, w2v.y, acc[q*4+1]));
      acc[q*4+2] = fmaf(a, w1v.z, fmaf(bs, w2v.z, acc[q*4+2]));
      acc[q*4+3] = fmaf(a, w1v.w, fmaf(bs, w2v.w, acc[q*4+3]));
    }
  }
#pragma unroll
  for (int i = 0; i < 16; ++i) m1s[el*129 + (jg<<4) + i] = fmaxf(acc[i], 0.f);
  __syncthreads();
  float acc2[16];
#pragma unroll
  for (int q = 0; q < 4; ++q) {
    float4 bb = *(const float4*)(b2 + (jg<<4) + (q<<2));
    acc2[q*4+0] = bb.x; acc2[q*4+1] = bb.y; acc2[q*4+2] = bb.z; acc2[q*4+3] = bb.w;
  }
  for (int k = 0; k < HD; ++k) {
    float a = m1s[el*129 + k];
    const float4* wp = (const float4*)(W2 + (size_t)k*HD + (jg<<4));
#pragma unroll
    for (int q = 0; q < 4; ++q) {
      float4 wv = wp[q];
      acc2[q*4+0] = fmaf(a, wv.x, acc2[q*4+0]);
      acc2[q*4+1] = fmaf(a, wv.y, acc2[q*4+1]);
      acc2[q*4+2] = fmaf(a, wv.z, acc2[q*4+2]);
      acc2[q*4+3] = fmaf(a, wv.w, acc2[q*4+3]);
    }
  }
#pragma unroll
  for (int i = 0; i < 16; ++i) hd[el*129 + (jg<<4) + i] = fmaxf(acc2[i], 0.f);
  __syncthreads();
  if (tid < HD) {
    int j = tid;
    for (int e = 0; e < 32; ++e) {
      int de = ldst[e];
      atomicAdd(&agg[(size_t)de*HD + j], hd[e*129 + j] * invd[de]);
    }
  }
}

// ---------------- fallback node update MLP (fp32) ----------------

__global__ __launch_bounds__(256) void k_upd(float* __restrict__ h, const float* __restrict__ agg,
                                             const float* __restrict__ pos,
                                             const float* __restrict__ W1, const float* __restrict__ b1,
                                             const float* __restrict__ W2, const float* __restrict__ b2,
                                             double* __restrict__ stats) {
  __shared__ float hs[32 * 129];
  __shared__ float as_[32 * 129];
  int tid = threadIdx.x;
  int base = blockIdx.x * 32;
#pragma unroll
  for (int r = 0; r < 16; ++r) {
    int lin = r*256 + tid;
    int n = lin >> 7, j = lin & 127;
    int gn = base + n;
    hs[n*129 + j]  = (gn < NN) ? h[(size_t)gn*HD + j]   : 0.f;
    as_[n*129 + j] = (gn < NN) ? agg[(size_t)gn*HD + j] : 0.f;
  }
  __syncthreads();
  int nl = tid & 31, jg = tid >> 5;
  int gn = base + nl;
  float var = (gn < NN) ? pos[gn*3+0] : 0.f;
  float acc[16];
#pragma unroll
  for (int q = 0; q < 4; ++q) {
    int j = (jg<<4) + (q<<2);
    float4 bb = *(const float4*)(b1 + j);
    float4 wv = *(const float4*)(W1 + 256*HD + j);
    acc[q*4+0] = fmaf(var, wv.x, bb.x);
    acc[q*4+1] = fmaf(var, wv.y, bb.y);
    acc[q*4+2] = fmaf(var, wv.z, bb.z);
    acc[q*4+3] = fmaf(var, wv.w, bb.w);
  }
  for (int k = 0; k < HD; ++k) {
    float a = hs[nl*129 + k];
    float g = as_[nl*129 + k];
    const float4* w1p = (const float4*)(W1 + (size_t)k*HD + (jg<<4));
    const float4* w2p = (const float4*)(W1 + (size_t)(128 + k)*HD + (jg<<4));
#pragma unroll
    for (int q = 0; q < 4; ++q) {
      float4 wa = w1p[q];
      float4 wb = w2p[q];
      acc[q*4+0] = fmaf(a, wa.x, fmaf(g, wb.x, acc[q*4+0]));
      acc[q*4+1] = fmaf(a, wa.y, fmaf(g, wb.y, acc[q*4+1]));
      acc[q*4+2] = fmaf(a, wa.z, fmaf(g, wb.z, acc[q*4+2]));
      acc[q*4+3] = fmaf(a, wa.w, fmaf(g, wb.w, acc[q*4+3]));
    }
  }
  float up1[16];
#pragma unroll
  for (int i = 0; i < 16; ++i) up1[i] = fmaxf(acc[i], 0.f);
  __syncthreads();
#pragma unroll
  for (int i = 0; i < 16; ++i) as_[nl*129 + (jg<<4) + i] = up1[i];
  __syncthreads();
  float acc2[16];
#pragma unroll
  for (int q = 0; q < 4; ++q) {
    float4 bb = *(const float4*)(b2 + (jg<<4) + (q<<2));
    acc2[q*4+0] = bb.x; acc2[q*4+1] = bb.y; acc2[q*4+2] = bb.z; acc2[q*4+3] = bb.w;
  }
  for (int k = 0; k < HD; ++k) {
    float a = as_[nl*129 + k];
    const float4* wp = (const float4*)(W2 + (size_t)k*HD + (jg<<4));
#pragma unroll
    for (int q = 0; q < 4; ++q) {
      float4 wv = wp[q];
      acc2[q*4+0] = fmaf(a, wv.x, acc2[q*4+0]);
      acc2[q*4+1] = fmaf(a, wv.y, acc2[q*4+1]);
      acc2[q*4+2] = fmaf(a, wv.z, acc2[q*4+2]);
      acc2[q*4+3] = fmaf(a, wv.w, acc2[q*4+3]);
    }
  }
  float x[16];
#pragma unroll
  for (int i = 0; i < 16; ++i)
    x[i] = hs[nl*129 + (jg<<4) + i] + fmaxf(acc2[i], 0.f);
  if (gn < NN) {
#pragma unroll
    for (int q = 0; q < 4; ++q)
      *(float4*)(h + (size_t)gn*HD + (jg<<4) + (q<<2)) = make_float4(x[q*4+0], x[q*4+1], x[q*4+2], x[q*4+3]);
  }
  __syncthreads();
#pragma unroll
  for (int i = 0; i < 16; ++i) hs[nl*129 + (jg<<4) + i] = (gn < NN) ? x[i] : 0.f;
  __syncthreads();
  if (tid < HD) {
    double s = 0.0, sq = 0.0;
    for (int e = 0; e < 32; ++e) { double v = (double)hs[e*129 + tid]; s += v; sq += v*v; }
    atomicAdd(&stats[tid], s);
    atomicAdd(&stats[HD + tid], sq);
  }
}

// ---------------- CNN head (optional fused BN of last layer) ----------------

__global__ __launch_bounds__(256) void k_conv(const float* __restrict__ h,
                                              const float* __restrict__ musig,
                                              const float* __restrict__ g, const float* __restrict__ be,
                                              int applyBN,
                                              const float* __restrict__ c1W, const float* __restrict__ c1b,
                                              const float* __restrict__ c2W, const float* __restrict__ c2b,
                                              const float* __restrict__ c3W, const float* __restrict__ c3b,
                                              float* __restrict__ out) {
  __shared__ float xs[4][128];
  __shared__ float o1[4][152];
  __shared__ float o2[4][72];
  int tid = threadIdx.x;
  int w = tid >> 6, lane = tid & 63;
  int n = blockIdx.x * 4 + w;
#pragma unroll
  for (int half = 0; half < 2; ++half) {
    int j = half * 64 + lane;
    float v = h[(size_t)n*HD + j];
    if (applyBN) v = g[j] * (v - musig[j]) * musig[HD + j] + be[j];
    xs[w][j] = v;
  }
  __syncthreads();
  for (int o = lane; o < 152; o += 64) {
    int oc = o / 38, t = o % 38;
    float s = c1b[oc];
#pragma unroll
    for (int k = 0; k < 16; ++k) s = fmaf(xs[w][t*3 + k], c1W[oc*16 + k], s);
    o1[w][oc*38 + t] = fmaxf(s, 0.f);
  }
  __syncthreads();
  for (int o = lane; o < 72; o += 64) {
    int oc = o / 9, t = o % 9;
    float s = c2b[oc];
    for (int ic = 0; ic < 4; ++ic) {
#pragma unroll
      for (int k = 0; k < 12; ++k) s = fmaf(o1[w][ic*38 + t*3 + k], c2W[oc*48 + ic*12 + k], s);
    }
    o2[w][oc*9 + t] = fmaxf(s, 0.f);
  }
  __syncthreads();
  int ic = lane >> 3, k = lane & 7;
  float t3 = o2[w][ic*9 + k] * c3W[ic*8 + k];
  for (int off = 32; off; off >>= 1) t3 += __shfl_down(t3, off);
  if (lane == 0) out[n] = 0.001f * (t3 + c3b[0]);
}

// ---------------- launcher ----------------

extern "C" void kernel_launch(void* const* d_in, const int* in_sizes, int n_in,
                              void* d_out, int out_size, void* d_ws, size_t ws_size,
                              hipStream_t stream) {
  (void)out_size;
  float* out = (float*)d_out;

  static const int expect[27] = {
    50000, 150000, 1200000,
    512, 128, 128, 128,
    16384, 128, 128, 128,
    199680, 768, 98304, 768, 197376, 768, 98304, 768,
    768, 768,
    64, 4, 384, 8, 64, 1
  };
  if (n_in != 27) { k_code<<<1, 64, 0, stream>>>(out, 5000099.f); return; }
  for (int i = 0; i < 27; ++i)
    if (in_sizes[i] != expect[i]) { k_code<<<1, 64, 0, stream>>>(out, 5000100.f + (float)i); return; }

  const float* u    = (const float*)d_in[0];
  const float* pos  = (const float*)d_in[1];
  const int*   ei   = (const int*)d_in[2];
  const float* eW1  = (const float*)d_in[3];
  const float* eb1  = (const float*)d_in[4];
  const float* eg1  = (const float*)d_in[5];
  const float* ebe1 = (const float*)d_in[6];
  const float* eW2  = (const float*)d_in[7];
  const float* eb2  = (const float*)d_in[8];
  const float* eg2  = (const float*)d_in[9];
  const float* ebe2 = (const float*)d_in[10];
  const float* m1W  = (const float*)d_in[11];
  const float* m1b  = (const float*)d_in[12];
  const float* m2W  = (const float*)d_in[13];
  const float* m2b  = (const float*)d_in[14];
  const float* u1W  = (const float*)d_in[15];
  const float* u1b  = (const float*)d_in[16];
  const float* u2W  = (const float*)d_in[17];
  const float* u2b  = (const float*)d_in[18];
  const float* bng  = (const float*)d_in[19];
  const float* bnb  = (const float*)d_in[20];
  const float* c1W  = (const float*)d_in[21];
  const float* c1b  = (const float*)d_in[22];
  const float* c2W  = (const float*)d_in[23];
  const float* c2b  = (const float*)d_in[24];
  const float* c3W  = (const float*)d_in[25];
  const float* c3b  = (const float*)d_in[26];

  // ---- workspace ----
  char* wsp = (char*)d_ws;
  size_t off = 0;
  auto alloc = [&](size_t bytes) -> void* {
    void* p = wsp + off;
    off = (off + bytes + 255) & ~(size_t)255;
    return p;
  };
  double* stats  = (double*)alloc(256 * 8);
  float*  musig  = (float*)alloc(256 * 4);
  int*    deg    = (int*)alloc((size_t)NN * 4);
  int*    cursor = (int*)alloc((size_t)NN * 4);
  int*    blk    = (int*)alloc(256 * 4);
  float*  invd   = (float*)alloc((size_t)NN * 4);
  float*  h      = (float*)alloc((size_t)NN * HD * 4);
  float*  agg    = (float*)alloc((size_t)NN * HD * 4);
  double* P      = (double*)alloc((size_t)3200 * 256 * 8);
  size_t needed_direct = off;
  unsigned short* A = (unsigned short*)alloc((size_t)NN * HD * 2);
  unsigned short* B = (unsigned short*)alloc((size_t)NN * HD * 2);
  float*  sfeat  = (float*)alloc((size_t)NE * 4 * 4);
  int*    ssrc   = (int*)alloc((size_t)NE * 4);
  int*    sdst   = (int*)alloc((size_t)NE * 4);
  int*    rowstart = (int*)alloc((size_t)(NN + 1) * 4);
  unsigned short* w2t = (unsigned short*)alloc((size_t)NL * HD * HD * 2);
  unsigned short* u2t = (unsigned short*)alloc((size_t)NL * HD * HD * 2);
  unsigned short* u1t = (unsigned short*)alloc((size_t)NL * HD * 256 * 2);
  unsigned short* abt = (unsigned short*)alloc((size_t)NL * 256 * HD * 2);
  size_t needed_fast = off;

  if (ws_size < needed_direct) {
    k_code<<<1, 64, 0, stream>>>(out, (float)(9000000u + (unsigned)(ws_size >> 20)));
    return;
  }
  const bool fast = (ws_size >= needed_fast);

  const int nbN  = (NN + 255) / 256;
  const int nbE  = (NE + 255) / 256;
  const int nt32 = (NN + 31) / 32;
  const int nbBN = NN * HD / 256;
  const int nbMU = NN / DPB;   // 3125 blocks x 16 dsts

  // ---- degree / inverse degree (+ sort + bf16 weight transposes if fast) ----
  hipMemsetAsync(deg, 0, (size_t)NN * 4, stream);
  k_deg<<<nbE, 256, 0, stream>>>(ei, deg);
  k_scan1<<<nbN, 256, 0, stream>>>(deg, cursor, blk, invd);
  if (fast) {
    k_scan2<<<1, 256, 0, stream>>>(blk, nbN);
    k_scan3<<<nbN, 256, 0, stream>>>(cursor, blk, rowstart);
    k_scatter<<<nbE, 256, 0, stream>>>(ei, u, pos, cursor, ssrc, sdst, sfeat);
    k_w2t<<<(NL*HD*HD + 255) / 256, 256, 0, stream>>>(m2W, w2t);
    k_w2t<<<(NL*HD*HD + 255) / 256, 256, 0, stream>>>(u2W, u2t);
    k_u1t<<<(NL*HD*256 + 255) / 256, 256, 0, stream>>>(u1W, u1t);
    k_abt<<<(NL*256*HD + 255) / 256, 256, 0, stream>>>(m1W, abt);
  }

  // ---- embedding (partial-stats path) ----
  k_emb1<<<nt32, 256, 0, stream>>>(u, pos, eW1, eb1, h, P);
  k_redP<<<128, 256, 0, stream>>>(P, nt32, musig);
  k_bn<<<nbBN, 256, 0, stream>>>(h, musig, eg1, ebe1, 1);
  k_emb2<<<nt32, 256, 0, stream>>>(h, eW2, eb2, P);
  k_redP<<<128, 256, 0, stream>>>(P, nt32, musig);
  k_bn<<<nbBN, 256, 0, stream>>>(h, musig, eg2, ebe2, 0);

  // ---- message-passing layers ----
  for (int i = 0; i < NL; ++i) {
    if (fast) {
      k_ab_mfma<<<nt32, 256, 0, stream>>>(h, abt + (size_t)i * 256 * HD,
                                          musig, bng + (size_t)(i > 0 ? i - 1 : 0) * HD,
                                          bnb + (size_t)(i > 0 ? i - 1 : 0) * HD,
                                          (i > 0) ? 1 : 0, A, B);
      k_msgupd<<<nbMU, 256, 0, stream>>>(A, B, ssrc, sdst, sfeat, invd, rowstart,
                                         m1W + (size_t)i * 260 * HD, m1b + (size_t)i * HD,
                                         w2t + (size_t)i * HD * HD, m2b + (size_t)i * HD,
                                         h, pos,
                                         u1t + (size_t)i * HD * 256,
                                         u1W + (size_t)i * 32896 + 256 * HD,
                                         u1b + (size_t)i * HD,
                                         u2t + (size_t)i * HD * HD,
                                         u2b + (size_t)i * HD, P);
      k_redP<<<128, 256, 0, stream>>>(P, nbMU, musig);
    } else {
      hipMemsetAsync(agg, 0, (size_t)NN * HD * 4, stream);
      k_msg_direct<<<NE / 32, 256, 0, stream>>>(h, ei, u, pos, invd,
                                                m1W + (size_t)i * 260 * HD, m1b + (size_t)i * HD,
                                                m2W + (size_t)i * HD * HD, m2b + (size_t)i * HD, agg);
      hipMemsetAsync(stats, 0, 256 * 8, stream);
      k_upd<<<nt32, 256, 0, stream>>>(h, agg, pos,
                                      u1W + (size_t)i * 257 * HD, u1b + (size_t)i * HD,
                                      u2W + (size_t)i * HD * HD, u2b + (size_t)i * HD, stats);
      k_redA<<<1, 128, 0, stream>>>(stats, musig);
      k_bn<<<nbBN, 256, 0, stream>>>(h, musig, bng + (size_t)i * HD, bnb + (size_t)i * HD, 0);
    }
  }

  // ---- CNN head (fused BN of layer 5 in fast path) ----
  k_conv<<<NN / 4, 256, 0, stream>>>(h, musig, bng + (size_t)(NL - 1) * HD, bnb + (size_t)(NL - 1) * HD,
                                     fast ? 1 : 0,
                                     c1W, c1b, c2W, c2b, c3W, c3b, out);
}